// Round 1
// 701.075 us; speedup vs baseline: 1.0238x; 1.0238x over previous
//
#include <hip/hip_runtime.h>
#include <hip/hip_bf16.h>
#include <stdint.h>

typedef __attribute__((ext_vector_type(8))) short bf16x8;
typedef __attribute__((ext_vector_type(4))) float floatx4;
typedef __attribute__((ext_vector_type(4))) float f32x4;
typedef __attribute__((ext_vector_type(2))) float f32x2;

__device__ __forceinline__ float2 bf2f(uint32_t u) {
  float2 r;
  r.x = __uint_as_float(u << 16);
  r.y = __uint_as_float(u & 0xffff0000u);
  return r;
}
__device__ __forceinline__ uint16_t f2bf(float f) {
  uint32_t u = __float_as_uint(f);
  uint32_t r = (u + 0x7fffu + ((u >> 16) & 1u)) >> 16;
  return (uint16_t)r;
}
__device__ __forceinline__ uint32_t f2bf_pack(float a, float b) {
  return (uint32_t)f2bf(a) | ((uint32_t)f2bf(b) << 16);
}
__device__ __forceinline__ int iclamp(int v, int lo, int hi) {
  return v < lo ? lo : (v > hi ? hi : v);
}
__device__ __forceinline__ float lrelu(float v) { return v >= 0.f ? v : 0.2f * v; }

// accumulate 8 bf16 channels (one uint4) scaled by w into a[0..7] (static idx)
__device__ __forceinline__ void acc8(float* a, uint4 r, float w) {
  float2 f0 = bf2f(r.x), f1 = bf2f(r.y), f2 = bf2f(r.z), f3 = bf2f(r.w);
  a[0] += w * f0.x; a[1] += w * f0.y;
  a[2] += w * f1.x; a[3] += w * f1.y;
  a[4] += w * f2.x; a[5] += w * f2.y;
  a[6] += w * f3.x; a[7] += w * f3.y;
}

// ---------------- dtype detect: f32 words have exp field ~[90,160] ----------
__global__ void detect_k(const uint32_t* __restrict__ w, int* __restrict__ flag) {
  __shared__ int cnt;
  if (threadIdx.x == 0) cnt = 0;
  __syncthreads();
  uint32_t v = w[threadIdx.x];
  int e = (v >> 23) & 0xFF;
  if (e >= 90 && e <= 160) atomicAdd(&cnt, 1);
  __syncthreads();
  if (threadIdx.x == 0) *flag = (cnt >= 128) ? 1 : 0;  // 1 = f32, 0 = bf16
}

// ---------------- transpose+convert 5x 128x128 weights -> bf16, one launch --
__global__ void transp5_k(const void* __restrict__ W0, const void* __restrict__ W1,
                          const void* __restrict__ W2, const void* __restrict__ W3,
                          const void* __restrict__ W4, __hip_bfloat16* __restrict__ WT,
                          const int* __restrict__ flag) {
  int b = blockIdx.x;       // 0..319
  int w = b >> 6;           // which weight
  int i = (b & 63) * 256 + threadIdx.x;
  const void* W = (w == 0) ? W0 : (w == 1) ? W1 : (w == 2) ? W2 : (w == 3) ? W3 : W4;
  int k = i >> 7, n = i & 127;
  uint16_t h;
  if (*flag)
    h = f2bf(((const float*)W)[i]);
  else
    h = ((const uint16_t*)W)[i];
  ((uint16_t*)WT)[w * 16384 + n * 128 + k] = h;
}

// ---------------- [M,128] @ [128,128] via MFMA bf16 -------------------------
__global__ __launch_bounds__(256) void mm_xw(const void* __restrict__ Abase, size_t aoff,
                                             const __hip_bfloat16* __restrict__ WT,
                                             __hip_bfloat16* __restrict__ out, int M,
                                             const int* __restrict__ flag) {
  __shared__ __align__(16) __hip_bfloat16 w[128 * 136];
  int isf32 = *flag;
  int tid = threadIdx.x;
  for (int i = tid; i < 2048; i += 256) {
    int row = i >> 4, ch = i & 15;
    *(uint4*)&w[row * 136 + ch * 8] = *(const uint4*)&WT[row * 128 + ch * 8];
  }
  __syncthreads();
  int wave = tid >> 6, lane = tid & 63;
  int l15 = lane & 15, kq = (lane >> 4) * 8;
  int row0 = blockIdx.x * 64 + wave * 16;
  int m = row0 + l15;
  int mc = m < M ? m : M - 1;
  floatx4 acc[8];
#pragma unroll
  for (int t = 0; t < 8; t++) acc[t] = (floatx4){0.f, 0.f, 0.f, 0.f};
#pragma unroll
  for (int k0 = 0; k0 < 128; k0 += 32) {
    union { bf16x8 v; uint32_t u[4]; } au;
    size_t eoff = aoff + (size_t)mc * 128 + k0 + kq;
    if (isf32) {
      const f32x4* Af = (const f32x4*)((const float*)Abase + eoff);
      f32x4 f0 = __builtin_nontemporal_load(Af);
      f32x4 f1 = __builtin_nontemporal_load(Af + 1);
      au.u[0] = f2bf_pack(f0.x, f0.y);
      au.u[1] = f2bf_pack(f0.z, f0.w);
      au.u[2] = f2bf_pack(f1.x, f1.y);
      au.u[3] = f2bf_pack(f1.z, f1.w);
    } else {
      au.v = __builtin_nontemporal_load((const bf16x8*)((const __hip_bfloat16*)Abase + eoff));
    }
#pragma unroll
    for (int t = 0; t < 8; t++) {
      bf16x8 b = *(const bf16x8*)&w[(t * 16 + l15) * 136 + k0 + kq];
      acc[t] = __builtin_amdgcn_mfma_f32_16x16x32_bf16(au.v, b, acc[t], 0, 0, 0);
    }
  }
  int rbase = row0 + (lane >> 4) * 4;
  uint16_t* o16 = (uint16_t*)out;
#pragma unroll
  for (int r = 0; r < 4; r++) {
    int rr = rbase + r;
    if (rr < M) {
#pragma unroll
      for (int t = 0; t < 8; t++) o16[(size_t)rr * 128 + t * 16 + l15] = f2bf(acc[t][r]);
    }
  }
}

// ---------------- es[m,h] = sum_c h[m,h*32+c]*a[h,c] ------------------------
__global__ void alpha_dot(const __hip_bfloat16* __restrict__ h, const void* __restrict__ a,
                          float* __restrict__ e, int M, const int* __restrict__ flag) {
  int idx = blockIdx.x * 256 + threadIdx.x;
  if (idx >= M * 4) return;
  int isf32 = *flag;
  int m = idx >> 2, hh = idx & 3;
  const uint32_t* hp = (const uint32_t*)(h + (size_t)m * 128 + hh * 32);
  float s = 0.f;
  if (isf32) {
    const float2* ap = (const float2*)((const float*)a + hh * 32);
#pragma unroll
    for (int i = 0; i < 16; i++) {
      float2 hv = bf2f(hp[i]);
      float2 av = ap[i];
      s += hv.x * av.x + hv.y * av.y;
    }
  } else {
    const uint32_t* ap = (const uint32_t*)((const __hip_bfloat16*)a + hh * 32);
#pragma unroll
    for (int i = 0; i < 16; i++) {
      float2 hv = bf2f(hp[i]);
      float2 av = bf2f(ap[i]);
      s += hv.x * av.x + hv.y * av.y;
    }
  }
  e[idx] = s;
}

// ---------------- counting sort helpers ----------------
__global__ void zero2_i32(int* p, int* q, int n) {
  int i = blockIdx.x * 256 + threadIdx.x;
  if (i < n) { p[i] = 0; q[i] = 0; }
}
__global__ void hist_k(const int* __restrict__ dst, int* __restrict__ cnt, int E, int N) {
  int i = blockIdx.x * 256 + threadIdx.x;
  if (i < E) atomicAdd(&cnt[iclamp(dst[i], 0, N - 1)], 1);
}
__global__ void scan_partial(const int* __restrict__ in, int* __restrict__ out,
                             int* __restrict__ bsum, int n) {
  __shared__ int lds[256];
  int t = threadIdx.x;
  int base = blockIdx.x * 1024 + t * 4;
  int v[4];
  int s = 0;
#pragma unroll
  for (int j = 0; j < 4; j++) {
    v[j] = (base + j < n) ? in[base + j] : 0;
    s += v[j];
  }
  lds[t] = s;
  __syncthreads();
  for (int d = 1; d < 256; d <<= 1) {
    int x = 0;
    if (t >= d) x = lds[t - d];
    __syncthreads();
    if (t >= d) lds[t] += x;
    __syncthreads();
  }
  int run = (t > 0) ? lds[t - 1] : 0;
  if (t == 255) bsum[blockIdx.x] = lds[255];
#pragma unroll
  for (int j = 0; j < 4; j++) {
    if (base + j < n) out[base + j] = run;
    run += v[j];
  }
}
// parallel exclusive scan of bsum[0..nb), nb <= 256, one block of 256
__global__ void scan_small2(int* __restrict__ bsum, int nb) {
  __shared__ int lds[256];
  int t = threadIdx.x;
  int v = (t < nb) ? bsum[t] : 0;
  lds[t] = v;
  __syncthreads();
  for (int d = 1; d < 256; d <<= 1) {
    int x = 0;
    if (t >= d) x = lds[t - d];
    __syncthreads();
    if (t >= d) lds[t] += x;
    __syncthreads();
  }
  if (t < nb) bsum[t] = (t > 0) ? lds[t - 1] : 0;
}
// scan_add with optional fused dinv computation (phase 3)
__global__ void scan_add(int* out, const int* bsum, const int* __restrict__ cnt,
                         float* __restrict__ dinv, int n) {
  int i = blockIdx.x * 256 + threadIdx.x;
  if (i < n) {
    out[i] += bsum[i >> 10];
    if (dinv) dinv[i] = rsqrtf((float)max(cnt[i], 0) + 1.0f);
  }
}
__global__ void fill_k(const int* __restrict__ src, const int* __restrict__ dst,
                       const int* __restrict__ off, int* __restrict__ cur,
                       int* __restrict__ sorted, int E, int N) {
  int i = blockIdx.x * 256 + threadIdx.x;
  if (i < E) {
    int d = iclamp(dst[i], 0, N - 1);
    int p = off[d] + atomicAdd(&cur[d], 1);
    sorted[iclamp(p, 0, E - 1)] = src[i];
  }
}

// ---------------- GAT aggregation: one wave per dst ------------------------
// 4 groups x 16 lanes; each group loads one full 256B row per step via
// dwordx4 (16B/lane), unroll x2 => 8 edges in flight per wave-iteration.
// Partial sums reduced across groups with shfl_xor(16/32) butterfly.
__global__ __launch_bounds__(256) void gat_agg(
    const int* __restrict__ off, const int* __restrict__ cnt,
    const int* __restrict__ ssrc, const __hip_bfloat16* __restrict__ hs,
    const float* __restrict__ es, const float* __restrict__ ed,
    const void* __restrict__ xdst, const void* __restrict__ bias,
    void* __restrict__ outb, size_t ooff, int nt_out,
    int N, int Ns, int E, const int* __restrict__ flag) {
  int wid = (blockIdx.x * 256 + threadIdx.x) >> 6;
  if (wid >= N) return;
  int isf32 = *flag;
  int lane = threadIdx.x & 63;
  int g = lane >> 4, il = lane & 15;
  int hh = il >> 2;                 // head for channels il*8 .. il*8+7
  int c8 = il * 8;
  int deg = iclamp(cnt[wid], 0, E);
  int o = iclamp(off[wid], 0, E - deg);
  const int* sp = ssrc + o;
  float edv = ed[wid * 4 + hh];
  float a[8] = {0.f, 0.f, 0.f, 0.f, 0.f, 0.f, 0.f, 0.f};
  float wsum = 0.f;
  for (int e = 0; e < deg; e += 8) {
    int e0 = e + g, e1 = e0 + 4;
    if (e1 < deg) {
      int s0 = iclamp(sp[e0], 0, Ns - 1);
      int s1 = iclamp(sp[e1], 0, Ns - 1);
      uint4 r0 = *(const uint4*)&hs[(size_t)s0 * 128 + c8];
      uint4 r1 = *(const uint4*)&hs[(size_t)s1 * 128 + c8];
      float w0 = __expf(lrelu(es[s0 * 4 + hh] + edv));
      float w1 = __expf(lrelu(es[s1 * 4 + hh] + edv));
      wsum += w0 + w1;
      acc8(a, r0, w0);
      acc8(a, r1, w1);
    } else if (e0 < deg) {
      int s0 = iclamp(sp[e0], 0, Ns - 1);
      uint4 r0 = *(const uint4*)&hs[(size_t)s0 * 128 + c8];
      float w0 = __expf(lrelu(es[s0 * 4 + hh] + edv));
      wsum += w0;
      acc8(a, r0, w0);
    }
  }
  // reduce across the 4 groups (lanes il, il+16, il+32, il+48)
#pragma unroll
  for (int j = 0; j < 8; j++) {
    a[j] += __shfl_xor(a[j], 16);
    a[j] += __shfl_xor(a[j], 32);
  }
  wsum += __shfl_xor(wsum, 16);
  wsum += __shfl_xor(wsum, 32);
  float inv = 1.f / (wsum + 1e-16f);
  // epilogue: lane (g,il) owns channels cc, cc+1 (bijective over 128)
  int cc = c8 + g * 2;
  float v0, v1;
  if (g == 0)      { v0 = a[0]; v1 = a[1]; }
  else if (g == 1) { v0 = a[2]; v1 = a[3]; }
  else if (g == 2) { v0 = a[4]; v1 = a[5]; }
  else             { v0 = a[6]; v1 = a[7]; }
  v0 *= inv; v1 *= inv;
  float x0, x1, b0, b1;
  if (isf32) {
    const float* xf = (const float*)xdst + (size_t)wid * 128 + cc;
    x0 = xf[0]; x1 = xf[1];
    const float* bf_ = (const float*)bias + cc;
    b0 = bf_[0]; b1 = bf_[1];
  } else {
    float2 xf = bf2f(*(const uint32_t*)&((const __hip_bfloat16*)xdst)[(size_t)wid * 128 + cc]);
    float2 bv = bf2f(*(const uint32_t*)&((const __hip_bfloat16*)bias)[cc]);
    x0 = xf.x; x1 = xf.y; b0 = bv.x; b1 = bv.y;
  }
  float r0 = x0 + 0.5f * (v0 + b0);
  float r1 = x1 + 0.5f * (v1 + b1);
  if (isf32) {
    f32x2* op = (f32x2*)((float*)outb + ooff + (size_t)wid * 128 + cc);
    f32x2 rv = {r0, r1};
    if (nt_out) __builtin_nontemporal_store(rv, op);
    else *op = rv;
  } else {
    *(uint32_t*)&((uint16_t*)outb)[ooff + (size_t)wid * 128 + cc] = f2bf_pack(r0, r1);
  }
}

// ---------------- GCN aggregation: one wave per dst node --------------------
// same 4x16 structure; self-loop term added pre-reduce by group 0.
__global__ __launch_bounds__(256) void gcn_agg(
    const int* __restrict__ off, const int* __restrict__ cnt,
    const int* __restrict__ ssrc, const __hip_bfloat16* __restrict__ xw,
    const float* __restrict__ dinv, const void* __restrict__ x,
    const void* __restrict__ bias, void* __restrict__ outb, size_t ooff,
    int N, int E, const int* __restrict__ flag) {
  int wid = (blockIdx.x * 256 + threadIdx.x) >> 6;
  if (wid >= N) return;
  int isf32 = *flag;
  int lane = threadIdx.x & 63;
  int g = lane >> 4, il = lane & 15;
  int c8 = il * 8;
  int deg = iclamp(cnt[wid], 0, E);
  int o = iclamp(off[wid], 0, E - deg);
  const int* sp = ssrc + o;
  float di = dinv[wid];
  float a[8] = {0.f, 0.f, 0.f, 0.f, 0.f, 0.f, 0.f, 0.f};
  for (int e = 0; e < deg; e += 8) {
    int e0 = e + g, e1 = e0 + 4;
    if (e1 < deg) {
      int s0 = iclamp(sp[e0], 0, N - 1);
      int s1 = iclamp(sp[e1], 0, N - 1);
      uint4 r0 = *(const uint4*)&xw[(size_t)s0 * 128 + c8];
      uint4 r1 = *(const uint4*)&xw[(size_t)s1 * 128 + c8];
      float d0 = dinv[s0], d1 = dinv[s1];
      acc8(a, r0, d0);
      acc8(a, r1, d1);
    } else if (e0 < deg) {
      int s0 = iclamp(sp[e0], 0, N - 1);
      uint4 r0 = *(const uint4*)&xw[(size_t)s0 * 128 + c8];
      float d0 = dinv[s0];
      acc8(a, r0, d0);
    }
  }
  // self-loop: xw[wid] * di added once (group 0), final *di gives di^2 term
  if (g == 0) {
    uint4 sr = *(const uint4*)&xw[(size_t)wid * 128 + c8];
    acc8(a, sr, di);
  }
#pragma unroll
  for (int j = 0; j < 8; j++) {
    a[j] += __shfl_xor(a[j], 16);
    a[j] += __shfl_xor(a[j], 32);
  }
  int cc = c8 + g * 2;
  float v0, v1;
  if (g == 0)      { v0 = a[0]; v1 = a[1]; }
  else if (g == 1) { v0 = a[2]; v1 = a[3]; }
  else if (g == 2) { v0 = a[4]; v1 = a[5]; }
  else             { v0 = a[6]; v1 = a[7]; }
  float agg0 = di * v0;
  float agg1 = di * v1;
  float x0, x1, b0, b1;
  if (isf32) {
    f32x2 xf = __builtin_nontemporal_load(
        (const f32x2*)((const float*)x + (size_t)wid * 128 + cc));
    x0 = xf.x; x1 = xf.y;
    const float* bf_ = (const float*)bias + cc;
    b0 = bf_[0]; b1 = bf_[1];
  } else {
    float2 xf = bf2f(*(const uint32_t*)&((const __hip_bfloat16*)x)[(size_t)wid * 128 + cc]);
    float2 bv = bf2f(*(const uint32_t*)&((const __hip_bfloat16*)bias)[cc]);
    x0 = xf.x; x1 = xf.y; b0 = bv.x; b1 = bv.y;
  }
  float r0 = x0 + 0.2f * (agg0 + b0);
  float r1 = x1 + 0.2f * (agg1 + b1);
  if (isf32) {
    f32x2 rv = {r0, r1};
    __builtin_nontemporal_store(rv, (f32x2*)((float*)outb + ooff + (size_t)wid * 128 + cc));
  } else {
    *(uint32_t*)&((uint16_t*)outb)[ooff + (size_t)wid * 128 + cc] = f2bf_pack(r0, r1);
  }
}

extern "C" void kernel_launch(void* const* d_in, const int* in_sizes, int n_in,
                              void* d_out, int out_size, void* d_ws, size_t ws_size,
                              hipStream_t stream) {
  const void* xb = d_in[0];
  const void* xc = d_in[1];
  const void* xt = d_in[2];
  const void* Ws1 = d_in[3];
  const void* Wd1 = d_in[4];
  const void* a_s1 = d_in[5];
  const void* a_d1 = d_in[6];
  const void* b1 = d_in[7];
  const void* Ws2 = d_in[8];
  const void* Wd2 = d_in[9];
  const void* a_s2 = d_in[10];
  const void* a_d2 = d_in[11];
  const void* b2 = d_in[12];
  const void* Wg = d_in[13];
  const void* bg = d_in[14];
  const int* b2c_src = (const int*)d_in[15];
  const int* b2c_dst = (const int*)d_in[16];
  const int* c2t_src = (const int*)d_in[17];
  const int* c2t_dst = (const int*)d_in[18];
  const int* adj_src = (const int*)d_in[19];
  const int* adj_dst = (const int*)d_in[20];

  const int Nb = in_sizes[0] / 128, Nc = in_sizes[1] / 128, Nt = in_sizes[2] / 128;
  const int Ebc = in_sizes[15], Ect = in_sizes[17], Eadj = in_sizes[19];

  auto al = [](size_t x) { return (x + 255) & ~(size_t)255; };
  char* base = (char*)d_ws;

  size_t oFlag = 0;
  size_t oWT = 256;
  size_t oXW = oWT + al(5 * 16384 * 2);
  size_t oPool = oXW + al((size_t)Nb * 256);

  // phase 1 pool
  size_t p1 = oPool;
  size_t o_ed1 = p1; p1 += al((size_t)Nc * 16);
  size_t o_hd1 = p1;
  size_t ov = o_hd1;
  size_t o_es1 = ov; ov += al((size_t)Nb * 16);
  size_t o_cntc = ov; ov += al((size_t)Nc * 4);
  size_t o_offc = ov; ov += al((size_t)Nc * 4);
  size_t o_curc = ov; ov += al((size_t)Nc * 4);
  size_t o_srtbc = ov; ov += al((size_t)Ebc * 4);
  size_t o_bs1 = ov; ov += al(1024);
  size_t slot1 = al((size_t)Nc * 256);
  size_t end1 = o_hd1 + (ov - o_hd1 > slot1 ? ov - o_hd1 : slot1);

  // phase 2 pool
  size_t p2 = oPool;
  size_t o_hs2 = p2; p2 += al((size_t)Nc * 256);
  size_t o_hd2 = p2; p2 += al((size_t)Nt * 256);
  size_t o_es2 = p2; p2 += al((size_t)Nc * 16);
  size_t o_ed2 = p2; p2 += al((size_t)Nt * 16);
  size_t o_cntt = p2; p2 += al((size_t)Nt * 4);
  size_t o_offt = p2; p2 += al((size_t)Nt * 4);
  size_t o_curt = p2; p2 += al((size_t)Nt * 4);
  size_t o_srtct = p2; p2 += al((size_t)Ect * 4);
  size_t o_bs2 = p2; p2 += al(1024);
  size_t end2 = p2;

  // phase 3 pool
  size_t p3 = oPool;
  size_t o_cntb = p3; p3 += al((size_t)Nb * 4);
  size_t o_offb = p3; p3 += al((size_t)Nb * 4);
  size_t o_curb = p3; p3 += al((size_t)Nb * 4);
  size_t o_dinv = p3; p3 += al((size_t)Nb * 4);
  size_t o_srtadj = p3; p3 += al((size_t)Eadj * 4);
  size_t o_bs3 = p3; p3 += al(1024);
  size_t end3 = p3;

  size_t required = end1;
  if (end2 > required) required = end2;
  if (end3 > required) required = end3;
  if (required > ws_size) return;

  int* flag = (int*)(base + oFlag);
  __hip_bfloat16* WT = (__hip_bfloat16*)(base + oWT);
  __hip_bfloat16* XW = (__hip_bfloat16*)(base + oXW);

  const size_t off_b_out = 0;
  const size_t off_c_out = (size_t)Nb * 128;
  const size_t off_t_out = off_c_out + (size_t)Nc * 128;

  detect_k<<<1, 256, 0, stream>>>((const uint32_t*)Ws1, flag);

  transp5_k<<<320, 256, 0, stream>>>(Ws1, Wd1, Ws2, Wd2, Wg, WT, flag);

  // ================= Phase 1: GAT building -> cable =================
  {
    __hip_bfloat16* hd1 = (__hip_bfloat16*)(base + o_hd1);
    float* ed1 = (float*)(base + o_ed1);
    mm_xw<<<(Nc + 63) / 64, 256, 0, stream>>>(xc, 0, WT + 1 * 16384, hd1, Nc, flag);
    alpha_dot<<<(Nc * 4 + 255) / 256, 256, 0, stream>>>(hd1, a_d1, ed1, Nc, flag);
    float* es1 = (float*)(base + o_es1);
    int* cnt_c = (int*)(base + o_cntc);
    int* off_c = (int*)(base + o_offc);
    int* cur_c = (int*)(base + o_curc);
    int* srt = (int*)(base + o_srtbc);
    int* bsum = (int*)(base + o_bs1);
    mm_xw<<<(Nb + 63) / 64, 256, 0, stream>>>(xb, 0, WT + 0 * 16384, XW, Nb, flag);
    alpha_dot<<<(Nb * 4 + 255) / 256, 256, 0, stream>>>(XW, a_s1, es1, Nb, flag);
    zero2_i32<<<(Nc + 255) / 256, 256, 0, stream>>>(cnt_c, cur_c, Nc);
    hist_k<<<(Ebc + 255) / 256, 256, 0, stream>>>(b2c_dst, cnt_c, Ebc, Nc);
    int nblk = (Nc + 1023) / 1024;
    scan_partial<<<nblk, 256, 0, stream>>>(cnt_c, off_c, bsum, Nc);
    scan_small2<<<1, 256, 0, stream>>>(bsum, nblk);
    scan_add<<<(Nc + 255) / 256, 256, 0, stream>>>(off_c, bsum, nullptr, nullptr, Nc);
    fill_k<<<(Ebc + 255) / 256, 256, 0, stream>>>(b2c_src, b2c_dst, off_c, cur_c, srt, Ebc, Nc);
    gat_agg<<<(int)(((size_t)Nc * 64 + 255) / 256), 256, 0, stream>>>(
        off_c, cnt_c, srt, XW, es1, ed1, xc, b1, d_out, off_c_out, 0, Nc, Nb, Ebc, flag);
  }

  // ================= Phase 2: GAT cable(updated) -> transformer =================
  {
    __hip_bfloat16* hs2 = (__hip_bfloat16*)(base + o_hs2);
    __hip_bfloat16* hd2 = (__hip_bfloat16*)(base + o_hd2);
    float* es2 = (float*)(base + o_es2);
    float* ed2 = (float*)(base + o_ed2);
    int* cnt_t = (int*)(base + o_cntt);
    int* off_t = (int*)(base + o_offt);
    int* cur_t = (int*)(base + o_curt);
    int* srt = (int*)(base + o_srtct);
    int* bsum = (int*)(base + o_bs2);
    mm_xw<<<(Nc + 63) / 64, 256, 0, stream>>>(d_out, off_c_out, WT + 2 * 16384, hs2, Nc, flag);
    mm_xw<<<(Nt + 63) / 64, 256, 0, stream>>>(xt, 0, WT + 3 * 16384, hd2, Nt, flag);
    alpha_dot<<<(Nc * 4 + 255) / 256, 256, 0, stream>>>(hs2, a_s2, es2, Nc, flag);
    alpha_dot<<<(Nt * 4 + 255) / 256, 256, 0, stream>>>(hd2, a_d2, ed2, Nt, flag);
    zero2_i32<<<(Nt + 255) / 256, 256, 0, stream>>>(cnt_t, cur_t, Nt);
    hist_k<<<(Ect + 255) / 256, 256, 0, stream>>>(c2t_dst, cnt_t, Ect, Nt);
    int nblk = (Nt + 1023) / 1024;
    scan_partial<<<nblk, 256, 0, stream>>>(cnt_t, off_t, bsum, Nt);
    scan_small2<<<1, 256, 0, stream>>>(bsum, nblk);
    scan_add<<<(Nt + 255) / 256, 256, 0, stream>>>(off_t, bsum, nullptr, nullptr, Nt);
    fill_k<<<(Ect + 255) / 256, 256, 0, stream>>>(c2t_src, c2t_dst, off_t, cur_t, srt, Ect, Nt);
    gat_agg<<<(int)(((size_t)Nt * 64 + 255) / 256), 256, 0, stream>>>(
        off_t, cnt_t, srt, hs2, es2, ed2, xt, b2, d_out, off_t_out, 1, Nt, Nc, Ect, flag);
  }

  // ================= Phase 3: GCN building adjacency =================
  {
    int* cnt_b = (int*)(base + o_cntb);
    int* off_b = (int*)(base + o_offb);
    int* cur_b = (int*)(base + o_curb);
    float* dinv = (float*)(base + o_dinv);
    int* srt = (int*)(base + o_srtadj);
    int* bsum = (int*)(base + o_bs3);
    mm_xw<<<(Nb + 63) / 64, 256, 0, stream>>>(xb, 0, WT + 4 * 16384, XW, Nb, flag);
    zero2_i32<<<(Nb + 255) / 256, 256, 0, stream>>>(cnt_b, cur_b, Nb);
    hist_k<<<(Eadj + 255) / 256, 256, 0, stream>>>(adj_dst, cnt_b, Eadj, Nb);
    int nblk = (Nb + 1023) / 1024;
    scan_partial<<<nblk, 256, 0, stream>>>(cnt_b, off_b, bsum, Nb);
    scan_small2<<<1, 256, 0, stream>>>(bsum, nblk);
    scan_add<<<(Nb + 255) / 256, 256, 0, stream>>>(off_b, bsum, cnt_b, dinv, Nb);
    fill_k<<<(Eadj + 255) / 256, 256, 0, stream>>>(adj_src, adj_dst, off_b, cur_b, srt, Eadj, Nb);
    gcn_agg<<<(int)(((size_t)Nb * 64 + 255) / 256), 256, 0, stream>>>(
        off_b, cnt_b, srt, XW, dinv, xb, bg, d_out, off_b_out, Nb, Eadj, flag);
  }
}

// Round 3
// 628.930 us; speedup vs baseline: 1.1412x; 1.1147x over previous
//
#include <hip/hip_runtime.h>
#include <hip/hip_bf16.h>
#include <stdint.h>

typedef __attribute__((ext_vector_type(8))) short bf16x8;
typedef __attribute__((ext_vector_type(4))) float floatx4;
typedef __attribute__((ext_vector_type(4))) float f32x4;
typedef __attribute__((ext_vector_type(2))) float f32x2;

__device__ __forceinline__ float2 bf2f(uint32_t u) {
  float2 r;
  r.x = __uint_as_float(u << 16);
  r.y = __uint_as_float(u & 0xffff0000u);
  return r;
}
__device__ __forceinline__ uint16_t f2bf(float f) {
  uint32_t u = __float_as_uint(f);
  uint32_t r = (u + 0x7fffu + ((u >> 16) & 1u)) >> 16;
  return (uint16_t)r;
}
__device__ __forceinline__ uint32_t f2bf_pack(float a, float b) {
  return (uint32_t)f2bf(a) | ((uint32_t)f2bf(b) << 16);
}
__device__ __forceinline__ int iclamp(int v, int lo, int hi) {
  return v < lo ? lo : (v > hi ? hi : v);
}
__device__ __forceinline__ float lrelu(float v) { return v >= 0.f ? v : 0.2f * v; }

// inline dtype detect from 64 words of Ws1 (wave ballot; wave-uniform result)
__device__ __forceinline__ int detect_f32(const uint32_t* __restrict__ det) {
  uint32_t v = det[threadIdx.x & 63];
  int e = (v >> 23) & 0xFF;
  unsigned long long b = __ballot(e >= 90 && e <= 160);
  return __popcll(b) >= 48;
}

// accumulate 8 bf16 channels (one uint4) scaled by w into a[0..7] (static idx)
__device__ __forceinline__ void acc8(float* a, uint4 r, float w) {
  float2 f0 = bf2f(r.x), f1 = bf2f(r.y), f2 = bf2f(r.z), f3 = bf2f(r.w);
  a[0] += w * f0.x; a[1] += w * f0.y;
  a[2] += w * f1.x; a[3] += w * f1.y;
  a[4] += w * f2.x; a[5] += w * f2.y;
  a[6] += w * f3.x; a[7] += w * f3.y;
}

// ---------------- transpose 5 weights -> bf16 WT, and zero cnt/cur ----------
__global__ void transp_zero(const void* __restrict__ W0, const void* __restrict__ W1,
                            const void* __restrict__ W2, const void* __restrict__ W3,
                            const void* __restrict__ W4, __hip_bfloat16* __restrict__ WT,
                            int* __restrict__ zp, int zn, const uint32_t* __restrict__ det) {
  int isf32 = detect_f32(det);
  int b = blockIdx.x;  // 0..319
  int w = b >> 6;
  int i = (b & 63) * 256 + threadIdx.x;
  const void* W = (w == 0) ? W0 : (w == 1) ? W1 : (w == 2) ? W2 : (w == 3) ? W3 : W4;
  int k = i >> 7, n = i & 127;
  uint16_t h;
  if (isf32)
    h = f2bf(((const float*)W)[i]);
  else
    h = ((const uint16_t*)W)[i];
  ((uint16_t*)WT)[w * 16384 + n * 128 + k] = h;
  for (int j = blockIdx.x * 256 + threadIdx.x; j < zn; j += gridDim.x * 256) zp[j] = 0;
}

// ---------------- histogram over 3 edge lists into concatenated cnt ---------
__global__ void hist_all(const int* __restrict__ d0, int E0, const int* __restrict__ d1,
                         int E1, const int* __restrict__ d2, int E2,
                         int* __restrict__ cnt, int n0, int n1, int n2) {
  int i = blockIdx.x * 256 + threadIdx.x;
  if (i < E0) {
    atomicAdd(&cnt[iclamp(d0[i], 0, n0 - 1)], 1);
  } else if (i < E0 + E1) {
    int j = i - E0;
    atomicAdd(&cnt[n0 + iclamp(d1[j], 0, n1 - 1)], 1);
  } else if (i < E0 + E1 + E2) {
    int j = i - E0 - E1;
    atomicAdd(&cnt[n0 + n1 + iclamp(d2[j], 0, n2 - 1)], 1);
  }
}

// ---------------- batched per-segment partial scan --------------------------
__global__ void scanp_all(const int* __restrict__ cnt, int* __restrict__ off,
                          int* __restrict__ bsum, int n0, int n1, int n2,
                          int nb0, int nb1) {
  int b = blockIdx.x;
  int seg, lb, base, n;
  if (b < nb0) { seg = 0; lb = b; base = 0; n = n0; }
  else if (b < nb0 + nb1) { seg = 1; lb = b - nb0; base = n0; n = n1; }
  else { seg = 2; lb = b - nb0 - nb1; base = n0 + n1; n = n2; }
  const int* in = cnt + base;
  int* out = off + base;
  int* bs = bsum + seg * 256;
  __shared__ int lds[256];
  int t = threadIdx.x;
  int pbase = lb * 1024 + t * 4;
  int v[4];
  int s = 0;
#pragma unroll
  for (int j = 0; j < 4; j++) {
    v[j] = (pbase + j < n) ? in[pbase + j] : 0;
    s += v[j];
  }
  lds[t] = s;
  __syncthreads();
  for (int d = 1; d < 256; d <<= 1) {
    int x = 0;
    if (t >= d) x = lds[t - d];
    __syncthreads();
    if (t >= d) lds[t] += x;
    __syncthreads();
  }
  int run = (t > 0) ? lds[t - 1] : 0;
  if (t == 255) bs[lb] = lds[255];
#pragma unroll
  for (int j = 0; j < 4; j++) {
    if (pbase + j < n) out[pbase + j] = run;
    run += v[j];
  }
}

// ---------------- 3-block scan of per-segment block sums --------------------
__global__ void scans_all(int* __restrict__ bsum, int nb0, int nb1, int nb2) {
  int seg = blockIdx.x;
  int nb = (seg == 0) ? nb0 : (seg == 1) ? nb1 : nb2;
  int* bs = bsum + seg * 256;
  __shared__ int lds[256];
  int t = threadIdx.x;
  int v = (t < nb) ? bs[t] : 0;
  lds[t] = v;
  __syncthreads();
  for (int d = 1; d < 256; d <<= 1) {
    int x = 0;
    if (t >= d) x = lds[t - d];
    __syncthreads();
    if (t >= d) lds[t] += x;
    __syncthreads();
  }
  if (t < nb) bs[t] = (t > 0) ? lds[t - 1] : 0;
}

// ---------------- scan_add over concatenated offsets, dinv fused (seg 2) ----
__global__ void scanadd_dinv(int* __restrict__ off, const int* __restrict__ bsum,
                             const int* __restrict__ cnt, float* __restrict__ dinv,
                             int n0, int n1, int n2) {
  int i = blockIdx.x * 256 + threadIdx.x;
  if (i >= n0 + n1 + n2) return;
  int seg, li;
  if (i < n0) { seg = 0; li = i; }
  else if (i < n0 + n1) { seg = 1; li = i - n0; }
  else { seg = 2; li = i - n0 - n1; }
  off[i] += bsum[seg * 256 + (li >> 10)];
  if (seg == 2) dinv[li] = rsqrtf((float)max(cnt[i], 0) + 1.0f);
}

// ---------------- batched fill of sorted-src arrays -------------------------
__global__ void fill_all(const int* __restrict__ s0, const int* __restrict__ d0, int E0,
                         const int* __restrict__ s1, const int* __restrict__ d1, int E1,
                         const int* __restrict__ s2, const int* __restrict__ d2, int E2,
                         const int* __restrict__ off, int* __restrict__ cur,
                         int* __restrict__ r0, int* __restrict__ r1, int* __restrict__ r2,
                         int n0, int n1, int n2) {
  int i = blockIdx.x * 256 + threadIdx.x;
  const int* sp;
  const int* dp;
  int* rp;
  int base, N, E, j;
  if (i < E0) { sp = s0; dp = d0; rp = r0; base = 0; N = n0; E = E0; j = i; }
  else if (i < E0 + E1) { sp = s1; dp = d1; rp = r1; base = n0; N = n1; E = E1; j = i - E0; }
  else if (i < E0 + E1 + E2) { sp = s2; dp = d2; rp = r2; base = n0 + n1; N = n2; E = E2; j = i - E0 - E1; }
  else return;
  int d = iclamp(dp[j], 0, N - 1);
  int gi = base + d;
  int p = off[gi] + atomicAdd(&cur[gi], 1);
  rp[iclamp(p, 0, E - 1)] = sp[j];
}

// ---------------- batched [M,128]@[128,128] MFMA with fused alpha-dot -------
struct MMB {
  const void* A0; const void* A1; const void* A2;
  unsigned long long ao0, ao1, ao2;  // element offsets into A
  const __hip_bfloat16* W0; const __hip_bfloat16* W1; const __hip_bfloat16* W2;
  __hip_bfloat16* O0; __hip_bfloat16* O1; __hip_bfloat16* O2;
  float* E0; float* E1; float* E2;       // es outputs (nullptr = skip)
  const void* V0; const void* V1; const void* V2;  // alpha vectors [128]
  int M0, M1, M2, B1, B2;                // block starts of mat1/mat2
};

__global__ __launch_bounds__(256) void mm_batch(MMB p, const uint32_t* __restrict__ det) {
  int isf32 = detect_f32(det);
  const void* Abase;
  size_t aoff;
  const __hip_bfloat16* WTp;
  __hip_bfloat16* out;
  float* esp;
  const void* av;
  int M, bRow;
  int bid = (int)blockIdx.x;
  if (bid >= p.B2) {
    Abase = p.A2; aoff = p.ao2; WTp = p.W2; out = p.O2; esp = p.E2; av = p.V2;
    M = p.M2; bRow = bid - p.B2;
  } else if (bid >= p.B1) {
    Abase = p.A1; aoff = p.ao1; WTp = p.W1; out = p.O1; esp = p.E1; av = p.V1;
    M = p.M1; bRow = bid - p.B1;
  } else {
    Abase = p.A0; aoff = p.ao0; WTp = p.W0; out = p.O0; esp = p.E0; av = p.V0;
    M = p.M0; bRow = bid;
  }
  __shared__ __align__(16) __hip_bfloat16 w[128 * 136];
  int tid = threadIdx.x;
  for (int i = tid; i < 2048; i += 256) {
    int row = i >> 4, ch = i & 15;
    *(uint4*)&w[row * 136 + ch * 8] = *(const uint4*)&WTp[row * 128 + ch * 8];
  }
  __syncthreads();
  int wave = tid >> 6, lane = tid & 63;
  int l15 = lane & 15, kq = (lane >> 4) * 8;
  int row0 = bRow * 64 + wave * 16;
  int m = row0 + l15;
  int mc = m < M ? m : M - 1;
  floatx4 acc[8];
#pragma unroll
  for (int t = 0; t < 8; t++) acc[t] = (floatx4){0.f, 0.f, 0.f, 0.f};
#pragma unroll
  for (int k0 = 0; k0 < 128; k0 += 32) {
    union { bf16x8 v; uint32_t u[4]; } au;
    size_t eoff = aoff + (size_t)mc * 128 + k0 + kq;
    if (isf32) {
      const f32x4* Af = (const f32x4*)((const float*)Abase + eoff);
      f32x4 f0 = __builtin_nontemporal_load(Af);
      f32x4 f1 = __builtin_nontemporal_load(Af + 1);
      au.u[0] = f2bf_pack(f0.x, f0.y);
      au.u[1] = f2bf_pack(f0.z, f0.w);
      au.u[2] = f2bf_pack(f1.x, f1.y);
      au.u[3] = f2bf_pack(f1.z, f1.w);
    } else {
      au.v = __builtin_nontemporal_load((const bf16x8*)((const __hip_bfloat16*)Abase + eoff));
    }
#pragma unroll
    for (int t = 0; t < 8; t++) {
      bf16x8 b = *(const bf16x8*)&w[(t * 16 + l15) * 136 + k0 + kq];
      acc[t] = __builtin_amdgcn_mfma_f32_16x16x32_bf16(au.v, b, acc[t], 0, 0, 0);
    }
  }
  int rbase = row0 + (lane >> 4) * 4;
  uint16_t* o16 = (uint16_t*)out;
#pragma unroll
  for (int r = 0; r < 4; r++) {
    int rr = rbase + r;
    if (rr < M) {
#pragma unroll
      for (int t = 0; t < 8; t++) o16[(size_t)rr * 128 + t * 16 + l15] = f2bf(acc[t][r]);
    }
  }
  // ---- fused alpha-dot: es[m,h] = sum_c C[m][h*32+c]*a[h*32+c] ----
  if (esp) {
    float av8[8];
    if (isf32) {
      const float* af = (const float*)av;
#pragma unroll
      for (int t = 0; t < 8; t++) av8[t] = af[t * 16 + l15];
    } else {
      const uint16_t* ab = (const uint16_t*)av;
#pragma unroll
      for (int t = 0; t < 8; t++) av8[t] = __uint_as_float((uint32_t)ab[t * 16 + l15] << 16);
    }
    float ph[4][4];
#pragma unroll
    for (int h = 0; h < 4; h++)
#pragma unroll
      for (int r = 0; r < 4; r++)
        ph[h][r] = acc[2 * h][r] * av8[2 * h] + acc[2 * h + 1][r] * av8[2 * h + 1];
#pragma unroll
    for (int h = 0; h < 4; h++)
#pragma unroll
      for (int r = 0; r < 4; r++) {
        float v = ph[h][r];
        v += __shfl_xor(v, 1);
        v += __shfl_xor(v, 2);
        v += __shfl_xor(v, 4);
        v += __shfl_xor(v, 8);
        ph[h][r] = v;
      }
    int rr = l15 >> 2, hh = l15 & 3;
    float s0 = (hh == 0) ? ph[0][0] : (hh == 1) ? ph[1][0] : (hh == 2) ? ph[2][0] : ph[3][0];
    float s1 = (hh == 0) ? ph[0][1] : (hh == 1) ? ph[1][1] : (hh == 2) ? ph[2][1] : ph[3][1];
    float s2 = (hh == 0) ? ph[0][2] : (hh == 1) ? ph[1][2] : (hh == 2) ? ph[2][2] : ph[3][2];
    float s3 = (hh == 0) ? ph[0][3] : (hh == 1) ? ph[1][3] : (hh == 2) ? ph[2][3] : ph[3][3];
    float val = (rr == 0) ? s0 : (rr == 1) ? s1 : (rr == 2) ? s2 : s3;
    int rowA = row0 + (lane >> 4) * 4 + rr;
    if (rowA < M) esp[(size_t)rowA * 4 + hh] = val;
  }
}

// ---------------- GAT aggregation: one wave per dst (4x16 groups) -----------
__global__ __launch_bounds__(256) void gat_agg(
    const int* __restrict__ off, const int* __restrict__ cnt,
    const int* __restrict__ ssrc, const __hip_bfloat16* __restrict__ hs,
    const float* __restrict__ es, const float* __restrict__ ed,
    const void* __restrict__ xdst, const void* __restrict__ bias,
    void* __restrict__ outb, size_t ooff, int nt_out,
    int N, int Ns, int E, const uint32_t* __restrict__ det) {
  int isf32 = detect_f32(det);
  int wid = (blockIdx.x * 256 + threadIdx.x) >> 6;
  if (wid >= N) return;
  int lane = threadIdx.x & 63;
  int g = lane >> 4, il = lane & 15;
  int hh = il >> 2;
  int c8 = il * 8;
  int deg = iclamp(cnt[wid], 0, E);
  int o = iclamp(off[wid], 0, E - deg);
  const int* sp = ssrc + o;
  float edv = ed[wid * 4 + hh];
  float a[8] = {0.f, 0.f, 0.f, 0.f, 0.f, 0.f, 0.f, 0.f};
  float wsum = 0.f;
  for (int e = 0; e < deg; e += 8) {
    int e0 = e + g, e1 = e0 + 4;
    if (e1 < deg) {
      int s0 = iclamp(sp[e0], 0, Ns - 1);
      int s1 = iclamp(sp[e1], 0, Ns - 1);
      uint4 r0 = *(const uint4*)&hs[(size_t)s0 * 128 + c8];
      uint4 r1 = *(const uint4*)&hs[(size_t)s1 * 128 + c8];
      float w0 = __expf(lrelu(es[s0 * 4 + hh] + edv));
      float w1 = __expf(lrelu(es[s1 * 4 + hh] + edv));
      wsum += w0 + w1;
      acc8(a, r0, w0);
      acc8(a, r1, w1);
    } else if (e0 < deg) {
      int s0 = iclamp(sp[e0], 0, Ns - 1);
      uint4 r0 = *(const uint4*)&hs[(size_t)s0 * 128 + c8];
      float w0 = __expf(lrelu(es[s0 * 4 + hh] + edv));
      wsum += w0;
      acc8(a, r0, w0);
    }
  }
#pragma unroll
  for (int j = 0; j < 8; j++) {
    a[j] += __shfl_xor(a[j], 16);
    a[j] += __shfl_xor(a[j], 32);
  }
  wsum += __shfl_xor(wsum, 16);
  wsum += __shfl_xor(wsum, 32);
  float inv = 1.f / (wsum + 1e-16f);
  int cc = c8 + g * 2;
  float v0, v1;
  if (g == 0)      { v0 = a[0]; v1 = a[1]; }
  else if (g == 1) { v0 = a[2]; v1 = a[3]; }
  else if (g == 2) { v0 = a[4]; v1 = a[5]; }
  else             { v0 = a[6]; v1 = a[7]; }
  v0 *= inv; v1 *= inv;
  float x0, x1, b0, b1;
  if (isf32) {
    const float* xf = (const float*)xdst + (size_t)wid * 128 + cc;
    x0 = xf[0]; x1 = xf[1];
    const float* bf_ = (const float*)bias + cc;
    b0 = bf_[0]; b1 = bf_[1];
  } else {
    float2 xf = bf2f(*(const uint32_t*)&((const __hip_bfloat16*)xdst)[(size_t)wid * 128 + cc]);
    float2 bv = bf2f(*(const uint32_t*)&((const __hip_bfloat16*)bias)[cc]);
    x0 = xf.x; x1 = xf.y; b0 = bv.x; b1 = bv.y;
  }
  float r0 = x0 + 0.5f * (v0 + b0);
  float r1 = x1 + 0.5f * (v1 + b1);
  if (isf32) {
    f32x2* op = (f32x2*)((float*)outb + ooff + (size_t)wid * 128 + cc);
    f32x2 rv = {r0, r1};
    if (nt_out) __builtin_nontemporal_store(rv, op);
    else *op = rv;
  } else {
    *(uint32_t*)&((uint16_t*)outb)[ooff + (size_t)wid * 128 + cc] = f2bf_pack(r0, r1);
  }
}

// ---------------- GCN aggregation: one wave per dst (4x16 groups) -----------
__global__ __launch_bounds__(256) void gcn_agg(
    const int* __restrict__ off, const int* __restrict__ cnt,
    const int* __restrict__ ssrc, const __hip_bfloat16* __restrict__ xw,
    const float* __restrict__ dinv, const void* __restrict__ x,
    const void* __restrict__ bias, void* __restrict__ outb, size_t ooff,
    int N, int E, const uint32_t* __restrict__ det) {
  int isf32 = detect_f32(det);
  int wid = (blockIdx.x * 256 + threadIdx.x) >> 6;
  if (wid >= N) return;
  int lane = threadIdx.x & 63;
  int g = lane >> 4, il = lane & 15;
  int c8 = il * 8;
  int deg = iclamp(cnt[wid], 0, E);
  int o = iclamp(off[wid], 0, E - deg);
  const int* sp = ssrc + o;
  float di = dinv[wid];
  float a[8] = {0.f, 0.f, 0.f, 0.f, 0.f, 0.f, 0.f, 0.f};
  for (int e = 0; e < deg; e += 8) {
    int e0 = e + g, e1 = e0 + 4;
    if (e1 < deg) {
      int s0 = iclamp(sp[e0], 0, N - 1);
      int s1 = iclamp(sp[e1], 0, N - 1);
      uint4 r0 = *(const uint4*)&xw[(size_t)s0 * 128 + c8];
      uint4 r1 = *(const uint4*)&xw[(size_t)s1 * 128 + c8];
      float d0 = dinv[s0], d1 = dinv[s1];
      acc8(a, r0, d0);
      acc8(a, r1, d1);
    } else if (e0 < deg) {
      int s0 = iclamp(sp[e0], 0, N - 1);
      uint4 r0 = *(const uint4*)&xw[(size_t)s0 * 128 + c8];
      float d0 = dinv[s0];
      acc8(a, r0, d0);
    }
  }
  if (g == 0) {
    uint4 sr = *(const uint4*)&xw[(size_t)wid * 128 + c8];
    acc8(a, sr, di);
  }
#pragma unroll
  for (int j = 0; j < 8; j++) {
    a[j] += __shfl_xor(a[j], 16);
    a[j] += __shfl_xor(a[j], 32);
  }
  int cc = c8 + g * 2;
  float v0, v1;
  if (g == 0)      { v0 = a[0]; v1 = a[1]; }
  else if (g == 1) { v0 = a[2]; v1 = a[3]; }
  else if (g == 2) { v0 = a[4]; v1 = a[5]; }
  else             { v0 = a[6]; v1 = a[7]; }
  float agg0 = di * v0;
  float agg1 = di * v1;
  float x0, x1, b0, b1;
  if (isf32) {
    f32x2 xf = __builtin_nontemporal_load(
        (const f32x2*)((const float*)x + (size_t)wid * 128 + cc));
    x0 = xf.x; x1 = xf.y;
    const float* bf_ = (const float*)bias + cc;
    b0 = bf_[0]; b1 = bf_[1];
  } else {
    float2 xf = bf2f(*(const uint32_t*)&((const __hip_bfloat16*)x)[(size_t)wid * 128 + cc]);
    float2 bv = bf2f(*(const uint32_t*)&((const __hip_bfloat16*)bias)[cc]);
    x0 = xf.x; x1 = xf.y; b0 = bv.x; b1 = bv.y;
  }
  float r0 = x0 + 0.2f * (agg0 + b0);
  float r1 = x1 + 0.2f * (agg1 + b1);
  if (isf32) {
    f32x2 rv = {r0, r1};
    __builtin_nontemporal_store(rv, (f32x2*)((float*)outb + ooff + (size_t)wid * 128 + cc));
  } else {
    *(uint32_t*)&((uint16_t*)outb)[ooff + (size_t)wid * 128 + cc] = f2bf_pack(r0, r1);
  }
}

extern "C" void kernel_launch(void* const* d_in, const int* in_sizes, int n_in,
                              void* d_out, int out_size, void* d_ws, size_t ws_size,
                              hipStream_t stream) {
  const void* xb = d_in[0];
  const void* xc = d_in[1];
  const void* xt = d_in[2];
  const void* Ws1 = d_in[3];
  const void* Wd1 = d_in[4];
  const void* a_s1 = d_in[5];
  const void* a_d1 = d_in[6];
  const void* b1 = d_in[7];
  const void* Ws2 = d_in[8];
  const void* Wd2 = d_in[9];
  const void* a_s2 = d_in[10];
  const void* a_d2 = d_in[11];
  const void* b2 = d_in[12];
  const void* Wg = d_in[13];
  const void* bg = d_in[14];
  const int* b2c_src = (const int*)d_in[15];
  const int* b2c_dst = (const int*)d_in[16];
  const int* c2t_src = (const int*)d_in[17];
  const int* c2t_dst = (const int*)d_in[18];
  const int* adj_src = (const int*)d_in[19];
  const int* adj_dst = (const int*)d_in[20];

  const int Nb = in_sizes[0] / 128, Nc = in_sizes[1] / 128, Nt = in_sizes[2] / 128;
  const int Ebc = in_sizes[15], Ect = in_sizes[17], Eadj = in_sizes[19];
  const int nAll = Nc + Nt + Nb;
  const int Eall = Ebc + Ect + Eadj;

  auto al = [](size_t x) { return (x + 255) & ~(size_t)255; };
  char* base = (char*)d_ws;

  size_t o = 0;
  size_t o_WT = o;    o += al((size_t)5 * 16384 * 2);
  size_t o_cnt = o;   o += al((size_t)nAll * 4);
  size_t o_cur = o;   o += al((size_t)nAll * 4);
  size_t o_off = o;   o += al((size_t)nAll * 4);
  size_t o_dinv = o;  o += al((size_t)Nb * 4);
  size_t o_bsum = o;  o += al(3 * 256 * 4);
  size_t o_srtbc = o; o += al((size_t)Ebc * 4);
  size_t o_srtct = o; o += al((size_t)Ect * 4);
  size_t o_srtadj = o; o += al((size_t)Eadj * 4);
  size_t o_es1 = o;   o += al((size_t)Nb * 16);
  size_t o_ed1 = o;   o += al((size_t)Nc * 16);
  size_t o_es2 = o;   o += al((size_t)Nc * 16);
  size_t o_ed2 = o;   o += al((size_t)Nt * 16);
  size_t o_hd1 = o;   o += al((size_t)Nc * 256);
  size_t o_hd2 = o;   o += al((size_t)Nt * 256);
  size_t o_hs2 = o;   o += al((size_t)Nc * 256);
  size_t o_XW = o;    o += al((size_t)Nb * 256);
  if (o > ws_size) return;

  const uint32_t* det = (const uint32_t*)Ws1;
  __hip_bfloat16* WT = (__hip_bfloat16*)(base + o_WT);
  int* cnt = (int*)(base + o_cnt);
  int* cur = (int*)(base + o_cur);
  int* off = (int*)(base + o_off);
  float* dinv = (float*)(base + o_dinv);
  int* bsum = (int*)(base + o_bsum);
  int* srt_bc = (int*)(base + o_srtbc);
  int* srt_ct = (int*)(base + o_srtct);
  int* srt_adj = (int*)(base + o_srtadj);
  float* es1 = (float*)(base + o_es1);
  float* ed1 = (float*)(base + o_ed1);
  float* es2 = (float*)(base + o_es2);
  float* ed2 = (float*)(base + o_ed2);
  __hip_bfloat16* hd1 = (__hip_bfloat16*)(base + o_hd1);
  __hip_bfloat16* hd2 = (__hip_bfloat16*)(base + o_hd2);
  __hip_bfloat16* hs2 = (__hip_bfloat16*)(base + o_hs2);
  __hip_bfloat16* XW = (__hip_bfloat16*)(base + o_XW);

  const size_t off_b_out = 0;
  const size_t off_c_out = (size_t)Nb * 128;
  const size_t off_t_out = off_c_out + (size_t)Nc * 128;

  // seg order in cnt/cur/off: [cable(Nc) | transformer(Nt) | building(Nb)]
  int* cnt_c = cnt;
  int* cnt_t = cnt + Nc;
  int* cnt_b = cnt + Nc + Nt;
  int* off_c = off;
  int* off_t = off + Nc;
  int* off_b = off + Nc + Nt;

  // 1. weight transpose + zero cnt/cur
  int zn = (int)((o_off - o_cnt) / 4);
  transp_zero<<<320, 256, 0, stream>>>(Ws1, Wd1, Ws2, Wd2, Wg, WT, cnt, zn, det);

  // 2. histogram all three edge lists
  hist_all<<<(Eall + 255) / 256, 256, 0, stream>>>(b2c_dst, Ebc, c2t_dst, Ect, adj_dst,
                                                   Eadj, cnt, Nc, Nt, Nb);

  // 3-5. batched scans (+dinv)
  int nb0 = (Nc + 1023) / 1024, nb1 = (Nt + 1023) / 1024, nb2 = (Nb + 1023) / 1024;
  scanp_all<<<nb0 + nb1 + nb2, 256, 0, stream>>>(cnt, off, bsum, Nc, Nt, Nb, nb0, nb1);
  scans_all<<<3, 256, 0, stream>>>(bsum, nb0, nb1, nb2);
  scanadd_dinv<<<(nAll + 255) / 256, 256, 0, stream>>>(off, bsum, cnt, dinv, Nc, Nt, Nb);

  // 6. fill all three sorted-src arrays
  fill_all<<<(Eall + 255) / 256, 256, 0, stream>>>(b2c_src, b2c_dst, Ebc, c2t_src, c2t_dst,
                                                   Ect, adj_src, adj_dst, Eadj, off, cur,
                                                   srt_bc, srt_ct, srt_adj, Nc, Nt, Nb);

  // 7. batched GEMM #1: xb@Ws1->XW(+es1), xc@Wd1->hd1(+ed1), xt@Wd2->hd2(+ed2)
  {
    MMB p;
    p.A0 = xb; p.ao0 = 0; p.W0 = WT + 0 * 16384; p.O0 = XW; p.E0 = es1; p.V0 = a_s1; p.M0 = Nb;
    p.A1 = xc; p.ao1 = 0; p.W1 = WT + 1 * 16384; p.O1 = hd1; p.E1 = ed1; p.V1 = a_d1; p.M1 = Nc;
    p.A2 = xt; p.ao2 = 0; p.W2 = WT + 3 * 16384; p.O2 = hd2; p.E2 = ed2; p.V2 = a_d2; p.M2 = Nt;
    int g0 = (Nb + 63) / 64, g1 = (Nc + 63) / 64, g2 = (Nt + 63) / 64;
    p.B1 = g0; p.B2 = g0 + g1;
    mm_batch<<<g0 + g1 + g2, 256, 0, stream>>>(p, det);
  }

  // 8. GAT phase 1: building -> cable
  gat_agg<<<(int)(((size_t)Nc * 64 + 255) / 256), 256, 0, stream>>>(
      off_c, cnt_c, srt_bc, XW, es1, ed1, xc, b1, d_out, off_c_out, 0, Nc, Nb, Ebc, det);

  // 9. batched GEMM #2: h_cable@Ws2->hs2(+es2), xb@Wg->XW (XW now free)
  {
    MMB p;
    p.A0 = d_out; p.ao0 = off_c_out; p.W0 = WT + 2 * 16384; p.O0 = hs2; p.E0 = es2;
    p.V0 = a_s2; p.M0 = Nc;
    p.A1 = xb; p.ao1 = 0; p.W1 = WT + 4 * 16384; p.O1 = XW; p.E1 = nullptr;
    p.V1 = nullptr; p.M1 = Nb;
    p.A2 = xb; p.ao2 = 0; p.W2 = WT; p.O2 = XW; p.E2 = nullptr; p.V2 = nullptr; p.M2 = 0;
    int g0 = (Nc + 63) / 64, g1 = (Nb + 63) / 64;
    p.B1 = g0; p.B2 = g0 + g1;  // mat2 never selected
    mm_batch<<<g0 + g1, 256, 0, stream>>>(p, det);
  }

  // 10. GAT phase 2: cable -> transformer
  gat_agg<<<(int)(((size_t)Nt * 64 + 255) / 256), 256, 0, stream>>>(
      off_t, cnt_t, srt_ct, hs2, es2, ed2, xt, b2, d_out, off_t_out, 1, Nt, Nc, Ect, det);

  // 11. GCN: building adjacency
  gcn_agg<<<(int)(((size_t)Nb * 64 + 255) / 256), 256, 0, stream>>>(
      off_b, cnt_b, srt_adj, XW, dinv, xb, bg, d_out, off_b_out, Nb, Eadj, det);
}

// Round 5
// 609.836 us; speedup vs baseline: 1.1769x; 1.0313x over previous
//
#include <hip/hip_runtime.h>
#include <hip/hip_bf16.h>
#include <stdint.h>

typedef __attribute__((ext_vector_type(8))) short bf16x8;
typedef __attribute__((ext_vector_type(4))) float floatx4;
typedef __attribute__((ext_vector_type(4))) float f32x4;
typedef __attribute__((ext_vector_type(2))) float f32x2;

__device__ __forceinline__ float2 bf2f(uint32_t u) {
  float2 r;
  r.x = __uint_as_float(u << 16);
  r.y = __uint_as_float(u & 0xffff0000u);
  return r;
}
__device__ __forceinline__ uint16_t f2bf(float f) {
  uint32_t u = __float_as_uint(f);
  uint32_t r = (u + 0x7fffu + ((u >> 16) & 1u)) >> 16;
  return (uint16_t)r;
}
__device__ __forceinline__ uint32_t f2bf_pack(float a, float b) {
  return (uint32_t)f2bf(a) | ((uint32_t)f2bf(b) << 16);
}
__device__ __forceinline__ int iclamp(int v, int lo, int hi) {
  return v < lo ? lo : (v > hi ? hi : v);
}
__device__ __forceinline__ float lrelu(float v) { return v >= 0.f ? v : 0.2f * v; }

// inline dtype detect from 64 words of Ws1 (wave ballot; wave-uniform result)
__device__ __forceinline__ int detect_f32(const uint32_t* __restrict__ det) {
  uint32_t v = det[threadIdx.x & 63];
  int e = (v >> 23) & 0xFF;
  unsigned long long b = __ballot(e >= 90 && e <= 160);
  return __popcll(b) >= 48;
}

// accumulate 8 bf16 channels (one uint4) scaled by w into a[0..7] (static idx)
__device__ __forceinline__ void acc8(float* a, uint4 r, float w) {
  float2 f0 = bf2f(r.x), f1 = bf2f(r.y), f2 = bf2f(r.z), f3 = bf2f(r.w);
  a[0] += w * f0.x; a[1] += w * f0.y;
  a[2] += w * f1.x; a[3] += w * f1.y;
  a[4] += w * f2.x; a[5] += w * f2.y;
  a[6] += w * f3.x; a[7] += w * f3.y;
}

// ---------------- transpose 5 weights -> bf16 WT, and zero cnt/cur ----------
__global__ void transp_zero(const void* __restrict__ W0, const void* __restrict__ W1,
                            const void* __restrict__ W2, const void* __restrict__ W3,
                            const void* __restrict__ W4, __hip_bfloat16* __restrict__ WT,
                            int* __restrict__ zp, int zn, const uint32_t* __restrict__ det) {
  int isf32 = detect_f32(det);
  int b = blockIdx.x;  // 0..319
  int w = b >> 6;
  int i = (b & 63) * 256 + threadIdx.x;
  const void* W = (w == 0) ? W0 : (w == 1) ? W1 : (w == 2) ? W2 : (w == 3) ? W3 : W4;
  int k = i >> 7, n = i & 127;
  uint16_t h;
  if (isf32)
    h = f2bf(((const float*)W)[i]);
  else
    h = ((const uint16_t*)W)[i];
  ((uint16_t*)WT)[w * 16384 + n * 128 + k] = h;
  for (int j = blockIdx.x * 256 + threadIdx.x; j < zn; j += gridDim.x * 256) zp[j] = 0;
}

// ---------------- histogram over 3 edge lists into concatenated cnt ---------
__global__ void hist_all(const int* __restrict__ d0, int E0, const int* __restrict__ d1,
                         int E1, const int* __restrict__ d2, int E2,
                         int* __restrict__ cnt, int n0, int n1, int n2) {
  int i = blockIdx.x * 256 + threadIdx.x;
  if (i < E0) {
    atomicAdd(&cnt[iclamp(d0[i], 0, n0 - 1)], 1);
  } else if (i < E0 + E1) {
    int j = i - E0;
    atomicAdd(&cnt[n0 + iclamp(d1[j], 0, n1 - 1)], 1);
  } else if (i < E0 + E1 + E2) {
    int j = i - E0 - E1;
    atomicAdd(&cnt[n0 + n1 + iclamp(d2[j], 0, n2 - 1)], 1);
  }
}

// ---------------- batched per-segment partial scan --------------------------
__global__ void scanp_all(const int* __restrict__ cnt, int* __restrict__ off,
                          int* __restrict__ bsum, int n0, int n1, int n2,
                          int nb0, int nb1) {
  int b = blockIdx.x;
  int seg, lb, base, n;
  if (b < nb0) { seg = 0; lb = b; base = 0; n = n0; }
  else if (b < nb0 + nb1) { seg = 1; lb = b - nb0; base = n0; n = n1; }
  else { seg = 2; lb = b - nb0 - nb1; base = n0 + n1; n = n2; }
  const int* in = cnt + base;
  int* out = off + base;
  int* bs = bsum + seg * 256;
  __shared__ int lds[256];
  int t = threadIdx.x;
  int pbase = lb * 1024 + t * 4;
  int v[4];
  int s = 0;
#pragma unroll
  for (int j = 0; j < 4; j++) {
    v[j] = (pbase + j < n) ? in[pbase + j] : 0;
    s += v[j];
  }
  lds[t] = s;
  __syncthreads();
  for (int d = 1; d < 256; d <<= 1) {
    int x = 0;
    if (t >= d) x = lds[t - d];
    __syncthreads();
    if (t >= d) lds[t] += x;
    __syncthreads();
  }
  int run = (t > 0) ? lds[t - 1] : 0;
  if (t == 255) bs[lb] = lds[255];
#pragma unroll
  for (int j = 0; j < 4; j++) {
    if (pbase + j < n) out[pbase + j] = run;
    run += v[j];
  }
}

// ---------------- 3-block scan of per-segment block sums --------------------
__global__ void scans_all(int* __restrict__ bsum, int nb0, int nb1, int nb2) {
  int seg = blockIdx.x;
  int nb = (seg == 0) ? nb0 : (seg == 1) ? nb1 : nb2;
  int* bs = bsum + seg * 256;
  __shared__ int lds[256];
  int t = threadIdx.x;
  int v = (t < nb) ? bs[t] : 0;
  lds[t] = v;
  __syncthreads();
  for (int d = 1; d < 256; d <<= 1) {
    int x = 0;
    if (t >= d) x = lds[t - d];
    __syncthreads();
    if (t >= d) lds[t] += x;
    __syncthreads();
  }
  if (t < nb) bs[t] = (t > 0) ? lds[t - 1] : 0;
}

// ---------------- scan_add over concatenated offsets, dinv fused (seg 2) ----
__global__ void scanadd_dinv(int* __restrict__ off, const int* __restrict__ bsum,
                             const int* __restrict__ cnt, float* __restrict__ dinv,
                             int n0, int n1, int n2) {
  int i = blockIdx.x * 256 + threadIdx.x;
  if (i >= n0 + n1 + n2) return;
  int seg, li;
  if (i < n0) { seg = 0; li = i; }
  else if (i < n0 + n1) { seg = 1; li = i - n0; }
  else { seg = 2; li = i - n0 - n1; }
  off[i] += bsum[seg * 256 + (li >> 10)];
  if (seg == 2) dinv[li] = rsqrtf((float)max(cnt[i], 0) + 1.0f);
}

// ---------------- param structs --------------------------------------------
struct MMB {
  const void *A0, *A1, *A2, *A3;
  unsigned long long ao0, ao1, ao2, ao3;   // element offsets into A
  const __hip_bfloat16 *W0, *W1, *W2, *W3;
  __hip_bfloat16 *O0, *O1, *O2, *O3;       // nullptr = skip C-store
  float *E0, *E1, *E2, *E3;                // es outputs (nullptr = skip)
  const void *V0, *V1, *V2, *V3;           // alpha vectors [128]
  int M0, M1, M2, M3;
  int B1, B2, B3;                          // block starts (0x7fffffff = unused)
};

struct FillJ {
  const int *s0, *d0, *s1, *d1, *s2, *d2;
  int E0, E1, E2;
  const int* off;
  int* cur;
  int *r0, *r1, *r2;
  int n0, n1, n2;
};

struct AggJob {
  const int* off; const int* cnt; const int* ssrc;
  const __hip_bfloat16* tab;          // gather table
  const float* es; const float* ed;   // gat only
  const float* dinv;                  // gcn only
  const void* xdst; const void* bias;
  void* outb;
  unsigned long long ooff;
  int nt_out, N, Ns, E, isGcn;
};

// ---------------- [M,128]@[128,128] MFMA body with fused alpha-dot ----------
__device__ __forceinline__ void mm_body(const MMB& p, int bid, int isf32) {
  const void* Abase;
  size_t aoff;
  const __hip_bfloat16* WTp;
  __hip_bfloat16* out;
  float* esp;
  const void* av;
  int M, bRow;
  if (bid >= p.B3) {
    Abase = p.A3; aoff = p.ao3; WTp = p.W3; out = p.O3; esp = p.E3; av = p.V3;
    M = p.M3; bRow = bid - p.B3;
  } else if (bid >= p.B2) {
    Abase = p.A2; aoff = p.ao2; WTp = p.W2; out = p.O2; esp = p.E2; av = p.V2;
    M = p.M2; bRow = bid - p.B2;
  } else if (bid >= p.B1) {
    Abase = p.A1; aoff = p.ao1; WTp = p.W1; out = p.O1; esp = p.E1; av = p.V1;
    M = p.M1; bRow = bid - p.B1;
  } else {
    Abase = p.A0; aoff = p.ao0; WTp = p.W0; out = p.O0; esp = p.E0; av = p.V0;
    M = p.M0; bRow = bid;
  }
  __shared__ __align__(16) __hip_bfloat16 w[128 * 136];
  int tid = threadIdx.x;
  for (int i = tid; i < 2048; i += 256) {
    int row = i >> 4, ch = i & 15;
    *(uint4*)&w[row * 136 + ch * 8] = *(const uint4*)&WTp[row * 128 + ch * 8];
  }
  __syncthreads();
  int wave = tid >> 6, lane = tid & 63;
  int l15 = lane & 15, kq = (lane >> 4) * 8;
  int row0 = bRow * 64 + wave * 16;
  int m = row0 + l15;
  int mc = m < M ? m : M - 1;
  floatx4 acc[8];
#pragma unroll
  for (int t = 0; t < 8; t++) acc[t] = (floatx4){0.f, 0.f, 0.f, 0.f};
#pragma unroll
  for (int k0 = 0; k0 < 128; k0 += 32) {
    union { bf16x8 v; uint32_t u[4]; } au;
    size_t eoff = aoff + (size_t)mc * 128 + k0 + kq;
    if (isf32) {
      const f32x4* Af = (const f32x4*)((const float*)Abase + eoff);
      f32x4 f0 = __builtin_nontemporal_load(Af);
      f32x4 f1 = __builtin_nontemporal_load(Af + 1);
      au.u[0] = f2bf_pack(f0.x, f0.y);
      au.u[1] = f2bf_pack(f0.z, f0.w);
      au.u[2] = f2bf_pack(f1.x, f1.y);
      au.u[3] = f2bf_pack(f1.z, f1.w);
    } else {
      au.v = __builtin_nontemporal_load((const bf16x8*)((const __hip_bfloat16*)Abase + eoff));
    }
#pragma unroll
    for (int t = 0; t < 8; t++) {
      bf16x8 b = *(const bf16x8*)&w[(t * 16 + l15) * 136 + k0 + kq];
      acc[t] = __builtin_amdgcn_mfma_f32_16x16x32_bf16(au.v, b, acc[t], 0, 0, 0);
    }
  }
  if (out) {
    int rbase = row0 + (lane >> 4) * 4;
    uint16_t* o16 = (uint16_t*)out;
#pragma unroll
    for (int r = 0; r < 4; r++) {
      int rr = rbase + r;
      if (rr < M) {
#pragma unroll
        for (int t = 0; t < 8; t++) o16[(size_t)rr * 128 + t * 16 + l15] = f2bf(acc[t][r]);
      }
    }
  }
  // ---- fused alpha-dot: es[m,h] = sum_c C[m][h*32+c]*a[h*32+c] ----
  if (esp) {
    float av8[8];
    if (isf32) {
      const float* af = (const float*)av;
#pragma unroll
      for (int t = 0; t < 8; t++) av8[t] = af[t * 16 + l15];
    } else {
      const uint16_t* ab = (const uint16_t*)av;
#pragma unroll
      for (int t = 0; t < 8; t++) av8[t] = __uint_as_float((uint32_t)ab[t * 16 + l15] << 16);
    }
    float ph[4][4];
#pragma unroll
    for (int h = 0; h < 4; h++)
#pragma unroll
      for (int r = 0; r < 4; r++)
        ph[h][r] = acc[2 * h][r] * av8[2 * h] + acc[2 * h + 1][r] * av8[2 * h + 1];
#pragma unroll
    for (int h = 0; h < 4; h++)
#pragma unroll
      for (int r = 0; r < 4; r++) {
        float v = ph[h][r];
        v += __shfl_xor(v, 1);
        v += __shfl_xor(v, 2);
        v += __shfl_xor(v, 4);
        v += __shfl_xor(v, 8);
        ph[h][r] = v;
      }
    int rr = l15 >> 2, hh = l15 & 3;
    float s0 = (hh == 0) ? ph[0][0] : (hh == 1) ? ph[1][0] : (hh == 2) ? ph[2][0] : ph[3][0];
    float s1 = (hh == 0) ? ph[0][1] : (hh == 1) ? ph[1][1] : (hh == 2) ? ph[2][1] : ph[3][1];
    float s2 = (hh == 0) ? ph[0][2] : (hh == 1) ? ph[1][2] : (hh == 2) ? ph[2][2] : ph[3][2];
    float s3 = (hh == 0) ? ph[0][3] : (hh == 1) ? ph[1][3] : (hh == 2) ? ph[2][3] : ph[3][3];
    float val = (rr == 0) ? s0 : (rr == 1) ? s1 : (rr == 2) ? s2 : s3;
    int rowA = row0 + (lane >> 4) * 4 + rr;
    if (rowA < M) esp[(size_t)rowA * 4 + hh] = val;
  }
}

// ---------------- counting-sort fill body -----------------------------------
__device__ __forceinline__ void fill_body(const FillJ& f, int lb) {
  int i = lb * 256 + (int)threadIdx.x;
  const int* sp;
  const int* dp;
  int* rp;
  int base, N, E, j;
  if (i < f.E0) { sp = f.s0; dp = f.d0; rp = f.r0; base = 0; N = f.n0; E = f.E0; j = i; }
  else if (i < f.E0 + f.E1) { sp = f.s1; dp = f.d1; rp = f.r1; base = f.n0; N = f.n1; E = f.E1; j = i - f.E0; }
  else if (i < f.E0 + f.E1 + f.E2) { sp = f.s2; dp = f.d2; rp = f.r2; base = f.n0 + f.n1; N = f.n2; E = f.E2; j = i - f.E0 - f.E1; }
  else return;
  int d = iclamp(dp[j], 0, N - 1);
  int gi = base + d;
  int p = f.off[gi] + atomicAdd(&f.cur[gi], 1);
  rp[iclamp(p, 0, E - 1)] = sp[j];
}

// ---------------- fused mm + fill launch ------------------------------------
__global__ __launch_bounds__(256) void mm_fill(MMB p, FillJ f, int Gmm,
                                               const uint32_t* __restrict__ det) {
  int isf32 = detect_f32(det);
  int bid = (int)blockIdx.x;
  if (bid < Gmm)
    mm_body(p, bid, isf32);
  else
    fill_body(f, bid - Gmm);
}

// ---------------- GAT aggregation body (4x16 groups per wave) ---------------
__device__ __forceinline__ void gat_body(const AggJob& j, int lb, int isf32) {
  int wid = (lb * 256 + (int)threadIdx.x) >> 6;
  if (wid >= j.N) return;
  int lane = threadIdx.x & 63;
  int g = lane >> 4, il = lane & 15;
  int hh = il >> 2;
  int c8 = il * 8;
  int deg = iclamp(j.cnt[wid], 0, j.E);
  int o = iclamp(j.off[wid], 0, j.E - deg);
  const int* sp = j.ssrc + o;
  float edv = j.ed[wid * 4 + hh];
  float a[8] = {0.f, 0.f, 0.f, 0.f, 0.f, 0.f, 0.f, 0.f};
  float wsum = 0.f;
  for (int e = 0; e < deg; e += 8) {
    int e0 = e + g, e1 = e0 + 4;
    if (e1 < deg) {
      int s0 = iclamp(sp[e0], 0, j.Ns - 1);
      int s1 = iclamp(sp[e1], 0, j.Ns - 1);
      uint4 r0 = *(const uint4*)&j.tab[(size_t)s0 * 128 + c8];
      uint4 r1 = *(const uint4*)&j.tab[(size_t)s1 * 128 + c8];
      float w0 = __expf(lrelu(j.es[s0 * 4 + hh] + edv));
      float w1 = __expf(lrelu(j.es[s1 * 4 + hh] + edv));
      wsum += w0 + w1;
      acc8(a, r0, w0);
      acc8(a, r1, w1);
    } else if (e0 < deg) {
      int s0 = iclamp(sp[e0], 0, j.Ns - 1);
      uint4 r0 = *(const uint4*)&j.tab[(size_t)s0 * 128 + c8];
      float w0 = __expf(lrelu(j.es[s0 * 4 + hh] + edv));
      wsum += w0;
      acc8(a, r0, w0);
    }
  }
#pragma unroll
  for (int q = 0; q < 8; q++) {
    a[q] += __shfl_xor(a[q], 16);
    a[q] += __shfl_xor(a[q], 32);
  }
  wsum += __shfl_xor(wsum, 16);
  wsum += __shfl_xor(wsum, 32);
  float inv = 1.f / (wsum + 1e-16f);
  int cc = c8 + g * 2;
  float v0, v1;
  if (g == 0)      { v0 = a[0]; v1 = a[1]; }
  else if (g == 1) { v0 = a[2]; v1 = a[3]; }
  else if (g == 2) { v0 = a[4]; v1 = a[5]; }
  else             { v0 = a[6]; v1 = a[7]; }
  v0 *= inv; v1 *= inv;
  float x0, x1, b0, b1;
  if (isf32) {
    const float* xf = (const float*)j.xdst + (size_t)wid * 128 + cc;
    x0 = xf[0]; x1 = xf[1];
    const float* bf_ = (const float*)j.bias + cc;
    b0 = bf_[0]; b1 = bf_[1];
  } else {
    float2 xf = bf2f(*(const uint32_t*)&((const __hip_bfloat16*)j.xdst)[(size_t)wid * 128 + cc]);
    float2 bv = bf2f(*(const uint32_t*)&((const __hip_bfloat16*)j.bias)[cc]);
    x0 = xf.x; x1 = xf.y; b0 = bv.x; b1 = bv.y;
  }
  float r0 = x0 + 0.5f * (v0 + b0);
  float r1 = x1 + 0.5f * (v1 + b1);
  if (isf32) {
    f32x2* op = (f32x2*)((float*)j.outb + j.ooff + (size_t)wid * 128 + cc);
    f32x2 rv = {r0, r1};
    if (j.nt_out) __builtin_nontemporal_store(rv, op);
    else *op = rv;
  } else {
    *(uint32_t*)&((uint16_t*)j.outb)[j.ooff + (size_t)wid * 128 + cc] = f2bf_pack(r0, r1);
  }
}

// ---------------- GCN aggregation body (4x16 groups per wave) ---------------
__device__ __forceinline__ void gcn_body(const AggJob& j, int lb, int isf32) {
  int wid = (lb * 256 + (int)threadIdx.x) >> 6;
  if (wid >= j.N) return;
  int lane = threadIdx.x & 63;
  int g = lane >> 4, il = lane & 15;
  int c8 = il * 8;
  int deg = iclamp(j.cnt[wid], 0, j.E);
  int o = iclamp(j.off[wid], 0, j.E - deg);
  const int* sp = j.ssrc + o;
  float di = j.dinv[wid];
  float a[8] = {0.f, 0.f, 0.f, 0.f, 0.f, 0.f, 0.f, 0.f};
  for (int e = 0; e < deg; e += 8) {
    int e0 = e + g, e1 = e0 + 4;
    if (e1 < deg) {
      int s0 = iclamp(sp[e0], 0, j.Ns - 1);
      int s1 = iclamp(sp[e1], 0, j.Ns - 1);
      uint4 r0 = *(const uint4*)&j.tab[(size_t)s0 * 128 + c8];
      uint4 r1 = *(const uint4*)&j.tab[(size_t)s1 * 128 + c8];
      float d0 = j.dinv[s0], d1 = j.dinv[s1];
      acc8(a, r0, d0);
      acc8(a, r1, d1);
    } else if (e0 < deg) {
      int s0 = iclamp(sp[e0], 0, j.Ns - 1);
      uint4 r0 = *(const uint4*)&j.tab[(size_t)s0 * 128 + c8];
      float d0 = j.dinv[s0];
      acc8(a, r0, d0);
    }
  }
  if (g == 0) {
    uint4 sr = *(const uint4*)&j.tab[(size_t)wid * 128 + c8];
    acc8(a, sr, di);
  }
#pragma unroll
  for (int q = 0; q < 8; q++) {
    a[q] += __shfl_xor(a[q], 16);
    a[q] += __shfl_xor(a[q], 32);
  }
  int cc = c8 + g * 2;
  float v0, v1;
  if (g == 0)      { v0 = a[0]; v1 = a[1]; }
  else if (g == 1) { v0 = a[2]; v1 = a[3]; }
  else if (g == 2) { v0 = a[4]; v1 = a[5]; }
  else             { v0 = a[6]; v1 = a[7]; }
  float agg0 = di * v0;
  float agg1 = di * v1;
  float x0, x1, b0, b1;
  if (isf32) {
    f32x2 xf = __builtin_nontemporal_load(
        (const f32x2*)((const float*)j.xdst + (size_t)wid * 128 + cc));
    x0 = xf.x; x1 = xf.y;
    const float* bf_ = (const float*)j.bias + cc;
    b0 = bf_[0]; b1 = bf_[1];
  } else {
    float2 xf = bf2f(*(const uint32_t*)&((const __hip_bfloat16*)j.xdst)[(size_t)wid * 128 + cc]);
    float2 bv = bf2f(*(const uint32_t*)&((const __hip_bfloat16*)j.bias)[cc]);
    x0 = xf.x; x1 = xf.y; b0 = bv.x; b1 = bv.y;
  }
  float r0 = x0 + 0.2f * (agg0 + b0);
  float r1 = x1 + 0.2f * (agg1 + b1);
  if (isf32) {
    f32x2 rv = {r0, r1};
    __builtin_nontemporal_store(rv, (f32x2*)((float*)j.outb + j.ooff + (size_t)wid * 128 + cc));
  } else {
    *(uint32_t*)&((uint16_t*)j.outb)[j.ooff + (size_t)wid * 128 + cc] = f2bf_pack(r0, r1);
  }
}

// ---------------- fused dual-job aggregation launch --------------------------
__global__ __launch_bounds__(256) void agg_pair(AggJob j0, AggJob j1, int G0,
                                                const uint32_t* __restrict__ det) {
  int isf32 = detect_f32(det);
  int bid = (int)blockIdx.x;
  if (bid < G0) {
    if (j0.isGcn) gcn_body(j0, bid, isf32);
    else gat_body(j0, bid, isf32);
  } else {
    int lb = bid - G0;
    if (j1.isGcn) gcn_body(j1, lb, isf32);
    else gat_body(j1, lb, isf32);
  }
}

extern "C" void kernel_launch(void* const* d_in, const int* in_sizes, int n_in,
                              void* d_out, int out_size, void* d_ws, size_t ws_size,
                              hipStream_t stream) {
  const void* xb = d_in[0];
  const void* xc = d_in[1];
  const void* xt = d_in[2];
  const void* Ws1 = d_in[3];
  const void* Wd1 = d_in[4];
  const void* a_s1 = d_in[5];
  const void* a_d1 = d_in[6];
  const void* b1 = d_in[7];
  const void* Ws2 = d_in[8];
  const void* Wd2 = d_in[9];
  const void* a_s2 = d_in[10];
  const void* a_d2 = d_in[11];
  const void* b2 = d_in[12];
  const void* Wg = d_in[13];
  const void* bg = d_in[14];
  const int* b2c_src = (const int*)d_in[15];
  const int* b2c_dst = (const int*)d_in[16];
  const int* c2t_src = (const int*)d_in[17];
  const int* c2t_dst = (const int*)d_in[18];
  const int* adj_src = (const int*)d_in[19];
  const int* adj_dst = (const int*)d_in[20];

  const int Nb = in_sizes[0] / 128, Nc = in_sizes[1] / 128, Nt = in_sizes[2] / 128;
  const int Ebc = in_sizes[15], Ect = in_sizes[17], Eadj = in_sizes[19];
  const int nAll = Nc + Nt + Nb;
  const int Eall = Ebc + Ect + Eadj;
  const int BIG = 0x7fffffff;

  auto al = [](size_t x) { return (x + 255) & ~(size_t)255; };
  char* base = (char*)d_ws;

  size_t o = 0;
  size_t o_WT = o;     o += al((size_t)5 * 16384 * 2);
  size_t o_cnt = o;    o += al((size_t)nAll * 4);
  size_t o_cur = o;    o += al((size_t)nAll * 4);
  size_t o_off = o;    o += al((size_t)nAll * 4);
  size_t o_dinv = o;   o += al((size_t)Nb * 4);
  size_t o_bsum = o;   o += al(3 * 256 * 4);
  size_t o_srtbc = o;  o += al((size_t)Ebc * 4);
  size_t o_srtct = o;  o += al((size_t)Ect * 4);
  size_t o_srtadj = o; o += al((size_t)Eadj * 4);
  size_t o_es1 = o;    o += al((size_t)Nb * 16);
  size_t o_ed1 = o;    o += al((size_t)Nc * 16);
  size_t o_es2 = o;    o += al((size_t)Nc * 16);
  size_t o_ed2 = o;    o += al((size_t)Nt * 16);
  size_t o_hs2 = o;    o += al((size_t)Nc * 256);
  size_t o_XW = o;     o += al((size_t)Nb * 256);
  size_t endB = o;
  size_t o_XWg = o;    o += al((size_t)Nb * 256);
  size_t endA = o;
  if (endB > ws_size) return;
  const bool pathA = (endA <= ws_size);

  const uint32_t* det = (const uint32_t*)Ws1;
  __hip_bfloat16* WT = (__hip_bfloat16*)(base + o_WT);
  int* cnt = (int*)(base + o_cnt);
  int* cur = (int*)(base + o_cur);
  int* off = (int*)(base + o_off);
  float* dinv = (float*)(base + o_dinv);
  int* bsum = (int*)(base + o_bsum);
  int* srt_bc = (int*)(base + o_srtbc);
  int* srt_ct = (int*)(base + o_srtct);
  int* srt_adj = (int*)(base + o_srtadj);
  float* es1 = (float*)(base + o_es1);
  float* ed1 = (float*)(base + o_ed1);
  float* es2 = (float*)(base + o_es2);
  float* ed2 = (float*)(base + o_ed2);
  __hip_bfloat16* hs2 = (__hip_bfloat16*)(base + o_hs2);
  __hip_bfloat16* XW = (__hip_bfloat16*)(base + o_XW);
  __hip_bfloat16* XWg = (__hip_bfloat16*)(base + o_XWg);

  const size_t off_b_out = 0;
  const size_t off_c_out = (size_t)Nb * 128;
  const size_t off_t_out = off_c_out + (size_t)Nc * 128;

  // seg order in cnt/cur/off: [cable(Nc) | transformer(Nt) | building(Nb)]
  int* cnt_c = cnt;
  int* cnt_t = cnt + Nc;
  int* cnt_b = cnt + Nc + Nt;
  int* off_c = off;
  int* off_t = off + Nc;
  int* off_b = off + Nc + Nt;

  // L1: weight transpose + zero cnt/cur
  int zn = (int)((o_off - o_cnt) / 4);
  transp_zero<<<320, 256, 0, stream>>>(Ws1, Wd1, Ws2, Wd2, Wg, WT, cnt, zn, det);

  // L2: histogram all three edge lists
  hist_all<<<(Eall + 255) / 256, 256, 0, stream>>>(b2c_dst, Ebc, c2t_dst, Ect, adj_dst,
                                                   Eadj, cnt, Nc, Nt, Nb);

  // L3-L5: batched scans (+dinv)
  int nb0 = (Nc + 1023) / 1024, nb1 = (Nt + 1023) / 1024, nb2 = (Nb + 1023) / 1024;
  scanp_all<<<nb0 + nb1 + nb2, 256, 0, stream>>>(cnt, off, bsum, Nc, Nt, Nb, nb0, nb1);
  scans_all<<<3, 256, 0, stream>>>(bsum, nb0, nb1, nb2);
  scanadd_dinv<<<(nAll + 255) / 256, 256, 0, stream>>>(off, bsum, cnt, dinv, Nc, Nt, Nb);

  // fill job (shared by both paths)
  FillJ fj;
  fj.s0 = b2c_src; fj.d0 = b2c_dst; fj.s1 = c2t_src; fj.d1 = c2t_dst;
  fj.s2 = adj_src; fj.d2 = adj_dst;
  fj.E0 = Ebc; fj.E1 = Ect; fj.E2 = Eadj;
  fj.off = off; fj.cur = cur;
  fj.r0 = srt_bc; fj.r1 = srt_ct; fj.r2 = srt_adj;
  fj.n0 = Nc; fj.n1 = Nt; fj.n2 = Nb;
  int Gfill = (Eall + 255) / 256;

  int g0 = (Nb + 63) / 64, g1 = (Nc + 63) / 64, g2 = (Nt + 63) / 64;

  // L6: fused GEMM #1 + fill.
  // slots: xb@Ws1->XW(+es1), xc@Wd1->ed1 only, xt@Wd2->ed2 only,
  //        [path A] xb@Wg->XWg
  {
    MMB p;
    p.A0 = xb; p.ao0 = 0; p.W0 = WT + 0 * 16384; p.O0 = XW;      p.E0 = es1; p.V0 = a_s1; p.M0 = Nb;
    p.A1 = xc; p.ao1 = 0; p.W1 = WT + 1 * 16384; p.O1 = nullptr; p.E1 = ed1; p.V1 = a_d1; p.M1 = Nc;
    p.A2 = xt; p.ao2 = 0; p.W2 = WT + 3 * 16384; p.O2 = nullptr; p.E2 = ed2; p.V2 = a_d2; p.M2 = Nt;
    p.A3 = xb; p.ao3 = 0; p.W3 = WT + 4 * 16384; p.O3 = XWg;     p.E3 = nullptr; p.V3 = nullptr; p.M3 = Nb;
    p.B1 = g0; p.B2 = g0 + g1;
    p.B3 = pathA ? (g0 + g1 + g2) : BIG;
    int Gmm = g0 + g1 + g2 + (pathA ? g0 : 0);
    mm_fill<<<Gmm + Gfill, 256, 0, stream>>>(p, fj, Gmm, det);
  }

  // agg jobs
  AggJob ja1;  // GAT phase 1: building -> cable
  ja1.off = off_c; ja1.cnt = cnt_c; ja1.ssrc = srt_bc; ja1.tab = XW;
  ja1.es = es1; ja1.ed = ed1; ja1.dinv = nullptr;
  ja1.xdst = xc; ja1.bias = b1; ja1.outb = d_out; ja1.ooff = off_c_out;
  ja1.nt_out = 0; ja1.N = Nc; ja1.Ns = Nb; ja1.E = Ebc; ja1.isGcn = 0;
  int Ga1 = (Nc + 3) / 4;

  AggJob jg;  // GCN: building adjacency
  jg.off = off_b; jg.cnt = cnt_b; jg.ssrc = srt_adj;
  jg.tab = pathA ? XWg : XW;
  jg.es = nullptr; jg.ed = nullptr; jg.dinv = dinv;
  jg.xdst = xb; jg.bias = bg; jg.outb = d_out; jg.ooff = off_b_out;
  jg.nt_out = 1; jg.N = Nb; jg.Ns = Nb; jg.E = Eadj; jg.isGcn = 1;
  int Gg = (Nb + 3) / 4;

  AggJob ja2;  // GAT phase 2: cable -> transformer
  ja2.off = off_t; ja2.cnt = cnt_t; ja2.ssrc = srt_ct; ja2.tab = hs2;
  ja2.es = es2; ja2.ed = ed2; ja2.dinv = nullptr;
  ja2.xdst = xt; ja2.bias = b2; ja2.outb = d_out; ja2.ooff = off_t_out;
  ja2.nt_out = 1; ja2.N = Nt; ja2.Ns = Nc; ja2.E = Ect; ja2.isGcn = 0;
  int Ga2 = (Nt + 3) / 4;

  if (pathA) {
    // L7: gcn (long) + gat1 (short) fused — independent after L6
    agg_pair<<<Gg + Ga1, 256, 0, stream>>>(jg, ja1, Gg, det);
    // L8: GEMM #2: h_cable@Ws2 -> hs2 (+es2)
    MMB p;
    p.A0 = d_out; p.ao0 = off_c_out; p.W0 = WT + 2 * 16384; p.O0 = hs2; p.E0 = es2; p.V0 = a_s2; p.M0 = Nc;
    p.A1 = nullptr; p.ao1 = 0; p.W1 = nullptr; p.O1 = nullptr; p.E1 = nullptr; p.V1 = nullptr; p.M1 = 0;
    p.A2 = nullptr; p.ao2 = 0; p.W2 = nullptr; p.O2 = nullptr; p.E2 = nullptr; p.V2 = nullptr; p.M2 = 0;
    p.A3 = nullptr; p.ao3 = 0; p.W3 = nullptr; p.O3 = nullptr; p.E3 = nullptr; p.V3 = nullptr; p.M3 = 0;
    p.B1 = BIG; p.B2 = BIG; p.B3 = BIG;
    mm_fill<<<g1, 256, 0, stream>>>(p, fj, g1, det);
    // L9: gat2 alone
    agg_pair<<<Ga2, 256, 0, stream>>>(ja2, ja2, Ga2, det);
  } else {
    // L7: gat1 alone
    agg_pair<<<Ga1, 256, 0, stream>>>(ja1, ja1, Ga1, det);
    // L8: GEMM #2: h_cable@Ws2 -> hs2 (+es2), xb@Wg -> XW (XW free after gat1)
    MMB p;
    p.A0 = d_out; p.ao0 = off_c_out; p.W0 = WT + 2 * 16384; p.O0 = hs2; p.E0 = es2; p.V0 = a_s2; p.M0 = Nc;
    p.A1 = xb; p.ao1 = 0; p.W1 = WT + 4 * 16384; p.O1 = XW; p.E1 = nullptr; p.V1 = nullptr; p.M1 = Nb;
    p.A2 = nullptr; p.ao2 = 0; p.W2 = nullptr; p.O2 = nullptr; p.E2 = nullptr; p.V2 = nullptr; p.M2 = 0;
    p.A3 = nullptr; p.ao3 = 0; p.W3 = nullptr; p.O3 = nullptr; p.E3 = nullptr; p.V3 = nullptr; p.M3 = 0;
    p.B1 = g1; p.B2 = BIG; p.B3 = BIG;
    mm_fill<<<g1 + g0, 256, 0, stream>>>(p, fj, g1 + g0, det);
    // L9: gcn (long) + gat2 (short) fused
    agg_pair<<<Gg + Ga2, 256, 0, stream>>>(jg, ja2, Gg, det);
  }
}

// Round 6
// 567.153 us; speedup vs baseline: 1.2655x; 1.0753x over previous
//
#include <hip/hip_runtime.h>
#include <hip/hip_bf16.h>
#include <stdint.h>

typedef __attribute__((ext_vector_type(8))) short bf16x8;
typedef __attribute__((ext_vector_type(4))) float floatx4;
typedef __attribute__((ext_vector_type(4))) float f32x4;
typedef __attribute__((ext_vector_type(2))) float f32x2;

__device__ __forceinline__ float2 bf2f(uint32_t u) {
  float2 r;
  r.x = __uint_as_float(u << 16);
  r.y = __uint_as_float(u & 0xffff0000u);
  return r;
}
__device__ __forceinline__ uint16_t f2bf(float f) {
  uint32_t u = __float_as_uint(f);
  uint32_t r = (u + 0x7fffu + ((u >> 16) & 1u)) >> 16;
  return (uint16_t)r;
}
__device__ __forceinline__ uint32_t f2bf_pack(float a, float b) {
  return (uint32_t)f2bf(a) | ((uint32_t)f2bf(b) << 16);
}
__device__ __forceinline__ int iclamp(int v, int lo, int hi) {
  return v < lo ? lo : (v > hi ? hi : v);
}
__device__ __forceinline__ float lrelu(float v) { return v >= 0.f ? v : 0.2f * v; }

// inline dtype detect from 64 words of Ws1 (wave ballot; wave-uniform result)
__device__ __forceinline__ int detect_f32(const uint32_t* __restrict__ det) {
  uint32_t v = det[threadIdx.x & 63];
  int e = (v >> 23) & 0xFF;
  unsigned long long b = __ballot(e >= 90 && e <= 160);
  return __popcll(b) >= 48;
}

// accumulate 8 bf16 channels (one uint4) scaled by w into a[0..7] (static idx)
__device__ __forceinline__ void acc8(float* a, uint4 r, float w) {
  float2 f0 = bf2f(r.x), f1 = bf2f(r.y), f2 = bf2f(r.z), f3 = bf2f(r.w);
  a[0] += w * f0.x; a[1] += w * f0.y;
  a[2] += w * f1.x; a[3] += w * f1.y;
  a[4] += w * f2.x; a[5] += w * f2.y;
  a[6] += w * f3.x; a[7] += w * f3.y;
}

// ---------------- fused: transpose 5 weights -> bf16 WT  +  histogram -------
// cnt/cur are zeroed by a preceding hipMemsetAsync on the stream.
__global__ void prep_k(const void* __restrict__ W0, const void* __restrict__ W1,
                       const void* __restrict__ W2, const void* __restrict__ W3,
                       const void* __restrict__ W4, __hip_bfloat16* __restrict__ WT,
                       const int* __restrict__ d0, int E0, const int* __restrict__ d1,
                       int E1, const int* __restrict__ d2, int E2,
                       int* __restrict__ cnt, int n0, int n1, int n2,
                       const uint32_t* __restrict__ det) {
  int b = blockIdx.x;
  if (b < 320) {
    int isf32 = detect_f32(det);
    int w = b >> 6;
    int i = (b & 63) * 256 + threadIdx.x;
    const void* W = (w == 0) ? W0 : (w == 1) ? W1 : (w == 2) ? W2 : (w == 3) ? W3 : W4;
    int k = i >> 7, n = i & 127;
    uint16_t h;
    if (isf32)
      h = f2bf(((const float*)W)[i]);
    else
      h = ((const uint16_t*)W)[i];
    ((uint16_t*)WT)[w * 16384 + n * 128 + k] = h;
  } else {
    int i = (b - 320) * 256 + threadIdx.x;
    if (i < E0) {
      atomicAdd(&cnt[iclamp(d0[i], 0, n0 - 1)], 1);
    } else if (i < E0 + E1) {
      int j = i - E0;
      atomicAdd(&cnt[n0 + iclamp(d1[j], 0, n1 - 1)], 1);
    } else if (i < E0 + E1 + E2) {
      int j = i - E0 - E1;
      atomicAdd(&cnt[n0 + n1 + iclamp(d2[j], 0, n2 - 1)], 1);
    }
  }
}

// ---------------- batched per-segment partial scan --------------------------
__global__ void scanp_all(const int* __restrict__ cnt, int* __restrict__ off,
                          int* __restrict__ bsum, int n0, int n1, int n2,
                          int nb0, int nb1) {
  int b = blockIdx.x;
  int seg, lb, base, n;
  if (b < nb0) { seg = 0; lb = b; base = 0; n = n0; }
  else if (b < nb0 + nb1) { seg = 1; lb = b - nb0; base = n0; n = n1; }
  else { seg = 2; lb = b - nb0 - nb1; base = n0 + n1; n = n2; }
  const int* in = cnt + base;
  int* out = off + base;
  int* bs = bsum + seg * 256;
  __shared__ int lds[256];
  int t = threadIdx.x;
  int pbase = lb * 1024 + t * 4;
  int v[4];
  int s = 0;
#pragma unroll
  for (int j = 0; j < 4; j++) {
    v[j] = (pbase + j < n) ? in[pbase + j] : 0;
    s += v[j];
  }
  lds[t] = s;
  __syncthreads();
  for (int d = 1; d < 256; d <<= 1) {
    int x = 0;
    if (t >= d) x = lds[t - d];
    __syncthreads();
    if (t >= d) lds[t] += x;
    __syncthreads();
  }
  int run = (t > 0) ? lds[t - 1] : 0;
  if (t == 255) bs[lb] = lds[255];
#pragma unroll
  for (int j = 0; j < 4; j++) {
    if (pbase + j < n) out[pbase + j] = run;
    run += v[j];
  }
}

// ---------------- 3-block scan of per-segment block sums --------------------
__global__ void scans_all(int* __restrict__ bsum, int nb0, int nb1, int nb2) {
  int seg = blockIdx.x;
  int nb = (seg == 0) ? nb0 : (seg == 1) ? nb1 : nb2;
  int* bs = bsum + seg * 256;
  __shared__ int lds[256];
  int t = threadIdx.x;
  int v = (t < nb) ? bs[t] : 0;
  lds[t] = v;
  __syncthreads();
  for (int d = 1; d < 256; d <<= 1) {
    int x = 0;
    if (t >= d) x = lds[t - d];
    __syncthreads();
    if (t >= d) lds[t] += x;
    __syncthreads();
  }
  if (t < nb) bs[t] = (t > 0) ? lds[t - 1] : 0;
}

// ---------------- scan_add over concatenated offsets, dinv fused (seg 2) ----
__global__ void scanadd_dinv(int* __restrict__ off, const int* __restrict__ bsum,
                             const int* __restrict__ cnt, float* __restrict__ dinv,
                             int n0, int n1, int n2) {
  int i = blockIdx.x * 256 + threadIdx.x;
  if (i >= n0 + n1 + n2) return;
  int seg, li;
  if (i < n0) { seg = 0; li = i; }
  else if (i < n0 + n1) { seg = 1; li = i - n0; }
  else { seg = 2; li = i - n0 - n1; }
  off[i] += bsum[seg * 256 + (li >> 10)];
  if (seg == 2) dinv[li] = rsqrtf((float)max(cnt[i], 0) + 1.0f);
}

// ---------------- param structs --------------------------------------------
struct MMB {
  const void *A0, *A1, *A2, *A3;
  unsigned long long ao0, ao1, ao2, ao3;   // element offsets into A
  const __hip_bfloat16 *W0, *W1, *W2, *W3;
  __hip_bfloat16 *O0, *O1, *O2, *O3;       // nullptr = skip C-store
  float *E0, *E1, *E2, *E3;                // es outputs (nullptr = skip)
  const void *V0, *V1, *V2, *V3;           // alpha vectors [128]
  int M0, M1, M2, M3;
  int B1, B2, B3;                          // block starts (0x7fffffff = unused)
  int dual;                                // slot0 also computes A0@W3 -> O3
};

struct FillJ {
  const int *s0, *d0, *s1, *d1, *s2, *d2;
  int E0, E1, E2;
  const int* off;
  int* cur;
  int *r0, *r1, *r2;
  int n0, n1, n2;
};

struct AggJob {
  const int* off; const int* cnt; const int* ssrc;
  const __hip_bfloat16* tab;          // gather table
  const float* es; const float* ed;   // gat only
  const float* dinv;                  // gcn only
  const void* xdst; const void* bias;
  void* outb;
  unsigned long long ooff;
  int nt_out, N, Ns, E, isGcn;
};

// ---------------- [M,128]@[128,128] MFMA body with fused alpha-dot ----------
__device__ __forceinline__ void mm_body(const MMB& p, int bid, int isf32) {
  const void* Abase;
  size_t aoff;
  const __hip_bfloat16* WTp;
  __hip_bfloat16* out;
  float* esp;
  const void* av;
  int M, bRow;
  if (bid >= p.B3) {
    Abase = p.A3; aoff = p.ao3; WTp = p.W3; out = p.O3; esp = p.E3; av = p.V3;
    M = p.M3; bRow = bid - p.B3;
  } else if (bid >= p.B2) {
    Abase = p.A2; aoff = p.ao2; WTp = p.W2; out = p.O2; esp = p.E2; av = p.V2;
    M = p.M2; bRow = bid - p.B2;
  } else if (bid >= p.B1) {
    Abase = p.A1; aoff = p.ao1; WTp = p.W1; out = p.O1; esp = p.E1; av = p.V1;
    M = p.M1; bRow = bid - p.B1;
  } else {
    Abase = p.A0; aoff = p.ao0; WTp = p.W0; out = p.O0; esp = p.E0; av = p.V0;
    M = p.M0; bRow = bid;
  }
  const bool dualThis = (p.dual != 0) && (bid < p.B1);
  __shared__ __align__(16) __hip_bfloat16 w[128 * 136];
  int tid = threadIdx.x;
  for (int i = tid; i < 2048; i += 256) {
    int row = i >> 4, ch = i & 15;
    *(uint4*)&w[row * 136 + ch * 8] = *(const uint4*)&WTp[row * 128 + ch * 8];
  }
  __syncthreads();
  int wave = tid >> 6, lane = tid & 63;
  int l15 = lane & 15, kq = (lane >> 4) * 8;
  int row0 = bRow * 64 + wave * 16;
  int m = row0 + l15;
  int mc = m < M ? m : M - 1;
  floatx4 acc[8];
#pragma unroll
  for (int t = 0; t < 8; t++) acc[t] = (floatx4){0.f, 0.f, 0.f, 0.f};
#pragma unroll
  for (int k0 = 0; k0 < 128; k0 += 32) {
    union { bf16x8 v; uint32_t u[4]; } au;
    size_t eoff = aoff + (size_t)mc * 128 + k0 + kq;
    if (isf32) {
      const f32x4* Af = (const f32x4*)((const float*)Abase + eoff);
      f32x4 f0, f1;
      if (dualThis) { f0 = Af[0]; f1 = Af[1]; }  // cached: pass 2 re-reads from L1
      else { f0 = __builtin_nontemporal_load(Af); f1 = __builtin_nontemporal_load(Af + 1); }
      au.u[0] = f2bf_pack(f0.x, f0.y);
      au.u[1] = f2bf_pack(f0.z, f0.w);
      au.u[2] = f2bf_pack(f1.x, f1.y);
      au.u[3] = f2bf_pack(f1.z, f1.w);
    } else {
      const bf16x8* Ab = (const bf16x8*)((const __hip_bfloat16*)Abase + eoff);
      au.v = dualThis ? *Ab : __builtin_nontemporal_load(Ab);
    }
#pragma unroll
    for (int t = 0; t < 8; t++) {
      bf16x8 b = *(const bf16x8*)&w[(t * 16 + l15) * 136 + k0 + kq];
      acc[t] = __builtin_amdgcn_mfma_f32_16x16x32_bf16(au.v, b, acc[t], 0, 0, 0);
    }
  }
  if (out) {
    int rbase = row0 + (lane >> 4) * 4;
    uint16_t* o16 = (uint16_t*)out;
#pragma unroll
    for (int r = 0; r < 4; r++) {
      int rr = rbase + r;
      if (rr < M) {
#pragma unroll
        for (int t = 0; t < 8; t++) o16[(size_t)rr * 128 + t * 16 + l15] = f2bf(acc[t][r]);
      }
    }
  }
  // ---- fused alpha-dot: es[m,h] = sum_c C[m][h*32+c]*a[h*32+c] ----
  if (esp) {
    float av8[8];
    if (isf32) {
      const float* af = (const float*)av;
#pragma unroll
      for (int t = 0; t < 8; t++) av8[t] = af[t * 16 + l15];
    } else {
      const uint16_t* ab = (const uint16_t*)av;
#pragma unroll
      for (int t = 0; t < 8; t++) av8[t] = __uint_as_float((uint32_t)ab[t * 16 + l15] << 16);
    }
    float ph[4][4];
#pragma unroll
    for (int h = 0; h < 4; h++)
#pragma unroll
      for (int r = 0; r < 4; r++)
        ph[h][r] = acc[2 * h][r] * av8[2 * h] + acc[2 * h + 1][r] * av8[2 * h + 1];
#pragma unroll
    for (int h = 0; h < 4; h++)
#pragma unroll
      for (int r = 0; r < 4; r++) {
        float v = ph[h][r];
        v += __shfl_xor(v, 1);
        v += __shfl_xor(v, 2);
        v += __shfl_xor(v, 4);
        v += __shfl_xor(v, 8);
        ph[h][r] = v;
      }
    int rr = l15 >> 2, hh = l15 & 3;
    float s0 = (hh == 0) ? ph[0][0] : (hh == 1) ? ph[1][0] : (hh == 2) ? ph[2][0] : ph[3][0];
    float s1 = (hh == 0) ? ph[0][1] : (hh == 1) ? ph[1][1] : (hh == 2) ? ph[2][1] : ph[3][1];
    float s2 = (hh == 0) ? ph[0][2] : (hh == 1) ? ph[1][2] : (hh == 2) ? ph[2][2] : ph[3][2];
    float s3 = (hh == 0) ? ph[0][3] : (hh == 1) ? ph[1][3] : (hh == 2) ? ph[2][3] : ph[3][3];
    float val = (rr == 0) ? s0 : (rr == 1) ? s1 : (rr == 2) ? s2 : s3;
    int rowA = row0 + (lane >> 4) * 4 + rr;
    if (rowA < M) esp[(size_t)rowA * 4 + hh] = val;
  }
  // ---- dual pass 2: same A panel (L1-hot) x W3 -> O3, no es ----
  if (dualThis) {
    __syncthreads();  // all waves done reading pass-1 LDS
    for (int i = tid; i < 2048; i += 256) {
      int row = i >> 4, ch = i & 15;
      *(uint4*)&w[row * 136 + ch * 8] = *(const uint4*)&p.W3[row * 128 + ch * 8];
    }
    __syncthreads();
    int mc2 = m < p.M3 ? m : p.M3 - 1;
    floatx4 acc2[8];
#pragma unroll
    for (int t = 0; t < 8; t++) acc2[t] = (floatx4){0.f, 0.f, 0.f, 0.f};
#pragma unroll
    for (int k0 = 0; k0 < 128; k0 += 32) {
      union { bf16x8 v; uint32_t u[4]; } au;
      size_t eoff = p.ao0 + (size_t)mc2 * 128 + k0 + kq;
      if (isf32) {
        const f32x4* Af = (const f32x4*)((const float*)p.A0 + eoff);
        f32x4 f0 = Af[0];
        f32x4 f1 = Af[1];
        au.u[0] = f2bf_pack(f0.x, f0.y);
        au.u[1] = f2bf_pack(f0.z, f0.w);
        au.u[2] = f2bf_pack(f1.x, f1.y);
        au.u[3] = f2bf_pack(f1.z, f1.w);
      } else {
        au.v = *(const bf16x8*)((const __hip_bfloat16*)p.A0 + eoff);
      }
#pragma unroll
      for (int t = 0; t < 8; t++) {
        bf16x8 b = *(const bf16x8*)&w[(t * 16 + l15) * 136 + k0 + kq];
        acc2[t] = __builtin_amdgcn_mfma_f32_16x16x32_bf16(au.v, b, acc2[t], 0, 0, 0);
      }
    }
    if (p.O3) {
      int rbase = row0 + (lane >> 4) * 4;
      uint16_t* o16 = (uint16_t*)p.O3;
#pragma unroll
      for (int r = 0; r < 4; r++) {
        int rr = rbase + r;
        if (rr < p.M3) {
#pragma unroll
          for (int t = 0; t < 8; t++) o16[(size_t)rr * 128 + t * 16 + l15] = f2bf(acc2[t][r]);
        }
      }
    }
  }
}

// ---------------- counting-sort fill body -----------------------------------
__device__ __forceinline__ void fill_body(const FillJ& f, int lb) {
  int i = lb * 256 + (int)threadIdx.x;
  const int* sp;
  const int* dp;
  int* rp;
  int base, N, E, j;
  if (i < f.E0) { sp = f.s0; dp = f.d0; rp = f.r0; base = 0; N = f.n0; E = f.E0; j = i; }
  else if (i < f.E0 + f.E1) { sp = f.s1; dp = f.d1; rp = f.r1; base = f.n0; N = f.n1; E = f.E1; j = i - f.E0; }
  else if (i < f.E0 + f.E1 + f.E2) { sp = f.s2; dp = f.d2; rp = f.r2; base = f.n0 + f.n1; N = f.n2; E = f.E2; j = i - f.E0 - f.E1; }
  else return;
  int d = iclamp(dp[j], 0, N - 1);
  int gi = base + d;
  int p = f.off[gi] + atomicAdd(&f.cur[gi], 1);
  rp[iclamp(p, 0, E - 1)] = sp[j];
}

// ---------------- fused mm + fill launch ------------------------------------
__global__ __launch_bounds__(256) void mm_fill(MMB p, FillJ f, int Gmm,
                                               const uint32_t* __restrict__ det) {
  int isf32 = detect_f32(det);
  int bid = (int)blockIdx.x;
  if (bid < Gmm)
    mm_body(p, bid, isf32);
  else
    fill_body(f, bid - Gmm);
}

// ---------------- GAT aggregation body (4x16 groups per wave) ---------------
__device__ __forceinline__ void gat_body(const AggJob& j, int lb, int isf32) {
  int wid = (lb * 256 + (int)threadIdx.x) >> 6;
  if (wid >= j.N) return;
  int lane = threadIdx.x & 63;
  int g = lane >> 4, il = lane & 15;
  int hh = il >> 2;
  int c8 = il * 8;
  int deg = iclamp(j.cnt[wid], 0, j.E);
  int o = iclamp(j.off[wid], 0, j.E - deg);
  const int* sp = j.ssrc + o;
  float edv = j.ed[wid * 4 + hh];
  float a[8] = {0.f, 0.f, 0.f, 0.f, 0.f, 0.f, 0.f, 0.f};
  float wsum = 0.f;
  for (int e = 0; e < deg; e += 8) {
    int e0 = e + g, e1 = e0 + 4;
    if (e1 < deg) {
      int s0 = iclamp(sp[e0], 0, j.Ns - 1);
      int s1 = iclamp(sp[e1], 0, j.Ns - 1);
      uint4 r0 = *(const uint4*)&j.tab[(size_t)s0 * 128 + c8];
      uint4 r1 = *(const uint4*)&j.tab[(size_t)s1 * 128 + c8];
      float w0 = __expf(lrelu(j.es[s0 * 4 + hh] + edv));
      float w1 = __expf(lrelu(j.es[s1 * 4 + hh] + edv));
      wsum += w0 + w1;
      acc8(a, r0, w0);
      acc8(a, r1, w1);
    } else if (e0 < deg) {
      int s0 = iclamp(sp[e0], 0, j.Ns - 1);
      uint4 r0 = *(const uint4*)&j.tab[(size_t)s0 * 128 + c8];
      float w0 = __expf(lrelu(j.es[s0 * 4 + hh] + edv));
      wsum += w0;
      acc8(a, r0, w0);
    }
  }
#pragma unroll
  for (int q = 0; q < 8; q++) {
    a[q] += __shfl_xor(a[q], 16);
    a[q] += __shfl_xor(a[q], 32);
  }
  wsum += __shfl_xor(wsum, 16);
  wsum += __shfl_xor(wsum, 32);
  float inv = 1.f / (wsum + 1e-16f);
  int cc = c8 + g * 2;
  float v0, v1;
  if (g == 0)      { v0 = a[0]; v1 = a[1]; }
  else if (g == 1) { v0 = a[2]; v1 = a[3]; }
  else if (g == 2) { v0 = a[4]; v1 = a[5]; }
  else             { v0 = a[6]; v1 = a[7]; }
  v0 *= inv; v1 *= inv;
  float x0, x1, b0, b1;
  if (isf32) {
    f32x2 xf = __builtin_nontemporal_load(
        (const f32x2*)((const float*)j.xdst + (size_t)wid * 128 + cc));
    x0 = xf.x; x1 = xf.y;
    const float* bf_ = (const float*)j.bias + cc;
    b0 = bf_[0]; b1 = bf_[1];
  } else {
    float2 xf = bf2f(*(const uint32_t*)&((const __hip_bfloat16*)j.xdst)[(size_t)wid * 128 + cc]);
    float2 bv = bf2f(*(const uint32_t*)&((const __hip_bfloat16*)j.bias)[cc]);
    x0 = xf.x; x1 = xf.y; b0 = bv.x; b1 = bv.y;
  }
  float r0 = x0 + 0.5f * (v0 + b0);
  float r1 = x1 + 0.5f * (v1 + b1);
  if (isf32) {
    f32x2* op = (f32x2*)((float*)j.outb + j.ooff + (size_t)wid * 128 + cc);
    f32x2 rv = {r0, r1};
    if (j.nt_out) __builtin_nontemporal_store(rv, op);
    else *op = rv;
  } else {
    *(uint32_t*)&((uint16_t*)j.outb)[j.ooff + (size_t)wid * 128 + cc] = f2bf_pack(r0, r1);
  }
}

// ---------------- GCN aggregation body (4x16 groups per wave) ---------------
__device__ __forceinline__ void gcn_body(const AggJob& j, int lb, int isf32) {
  int wid = (lb * 256 + (int)threadIdx.x) >> 6;
  if (wid >= j.N) return;
  int lane = threadIdx.x & 63;
  int g = lane >> 4, il = lane & 15;
  int c8 = il * 8;
  int deg = iclamp(j.cnt[wid], 0, j.E);
  int o = iclamp(j.off[wid], 0, j.E - deg);
  const int* sp = j.ssrc + o;
  float di = j.dinv[wid];
  float a[8] = {0.f, 0.f, 0.f, 0.f, 0.f, 0.f, 0.f, 0.f};
  for (int e = 0; e < deg; e += 8) {
    int e0 = e + g, e1 = e0 + 4;
    if (e1 < deg) {
      int s0 = iclamp(sp[e0], 0, j.Ns - 1);
      int s1 = iclamp(sp[e1], 0, j.Ns - 1);
      uint4 r0 = *(const uint4*)&j.tab[(size_t)s0 * 128 + c8];
      uint4 r1 = *(const uint4*)&j.tab[(size_t)s1 * 128 + c8];
      float d0 = j.dinv[s0], d1 = j.dinv[s1];
      acc8(a, r0, d0);
      acc8(a, r1, d1);
    } else if (e0 < deg) {
      int s0 = iclamp(sp[e0], 0, j.Ns - 1);
      uint4 r0 = *(const uint4*)&j.tab[(size_t)s0 * 128 + c8];
      float d0 = j.dinv[s0];
      acc8(a, r0, d0);
    }
  }
  if (g == 0) {
    uint4 sr = *(const uint4*)&j.tab[(size_t)wid * 128 + c8];
    acc8(a, sr, di);
  }
#pragma unroll
  for (int q = 0; q < 8; q++) {
    a[q] += __shfl_xor(a[q], 16);
    a[q] += __shfl_xor(a[q], 32);
  }
  int cc = c8 + g * 2;
  float v0, v1;
  if (g == 0)      { v0 = a[0]; v1 = a[1]; }
  else if (g == 1) { v0 = a[2]; v1 = a[3]; }
  else if (g == 2) { v0 = a[4]; v1 = a[5]; }
  else             { v0 = a[6]; v1 = a[7]; }
  float agg0 = di * v0;
  float agg1 = di * v1;
  float x0, x1, b0, b1;
  if (isf32) {
    f32x2 xf = __builtin_nontemporal_load(
        (const f32x2*)((const float*)j.xdst + (size_t)wid * 128 + cc));
    x0 = xf.x; x1 = xf.y;
    const float* bf_ = (const float*)j.bias + cc;
    b0 = bf_[0]; b1 = bf_[1];
  } else {
    float2 xf = bf2f(*(const uint32_t*)&((const __hip_bfloat16*)j.xdst)[(size_t)wid * 128 + cc]);
    float2 bv = bf2f(*(const uint32_t*)&((const __hip_bfloat16*)j.bias)[cc]);
    x0 = xf.x; x1 = xf.y; b0 = bv.x; b1 = bv.y;
  }
  float r0 = x0 + 0.2f * (agg0 + b0);
  float r1 = x1 + 0.2f * (agg1 + b1);
  if (isf32) {
    f32x2 rv = {r0, r1};
    __builtin_nontemporal_store(rv, (f32x2*)((float*)j.outb + j.ooff + (size_t)wid * 128 + cc));
  } else {
    *(uint32_t*)&((uint16_t*)j.outb)[j.ooff + (size_t)wid * 128 + cc] = f2bf_pack(r0, r1);
  }
}

// ---------------- fused dual-job aggregation launch --------------------------
__global__ __launch_bounds__(256) void agg_pair(AggJob j0, AggJob j1, int G0,
                                                const uint32_t* __restrict__ det) {
  int isf32 = detect_f32(det);
  int bid = (int)blockIdx.x;
  if (bid < G0) {
    if (j0.isGcn) gcn_body(j0, bid, isf32);
    else gat_body(j0, bid, isf32);
  } else {
    int lb = bid - G0;
    if (j1.isGcn) gcn_body(j1, lb, isf32);
    else gat_body(j1, lb, isf32);
  }
}

extern "C" void kernel_launch(void* const* d_in, const int* in_sizes, int n_in,
                              void* d_out, int out_size, void* d_ws, size_t ws_size,
                              hipStream_t stream) {
  const void* xb = d_in[0];
  const void* xc = d_in[1];
  const void* xt = d_in[2];
  const void* Ws1 = d_in[3];
  const void* Wd1 = d_in[4];
  const void* a_s1 = d_in[5];
  const void* a_d1 = d_in[6];
  const void* b1 = d_in[7];
  const void* Ws2 = d_in[8];
  const void* Wd2 = d_in[9];
  const void* a_s2 = d_in[10];
  const void* a_d2 = d_in[11];
  const void* b2 = d_in[12];
  const void* Wg = d_in[13];
  const void* bg = d_in[14];
  const int* b2c_src = (const int*)d_in[15];
  const int* b2c_dst = (const int*)d_in[16];
  const int* c2t_src = (const int*)d_in[17];
  const int* c2t_dst = (const int*)d_in[18];
  const int* adj_src = (const int*)d_in[19];
  const int* adj_dst = (const int*)d_in[20];

  const int Nb = in_sizes[0] / 128, Nc = in_sizes[1] / 128, Nt = in_sizes[2] / 128;
  const int Ebc = in_sizes[15], Ect = in_sizes[17], Eadj = in_sizes[19];
  const int nAll = Nc + Nt + Nb;
  const int Eall = Ebc + Ect + Eadj;
  const int BIG = 0x7fffffff;

  auto al = [](size_t x) { return (x + 255) & ~(size_t)255; };
  char* base = (char*)d_ws;

  size_t o = 0;
  size_t o_WT = o;     o += al((size_t)5 * 16384 * 2);
  size_t o_cnt = o;    o += al((size_t)nAll * 4);
  size_t o_cur = o;    o += al((size_t)nAll * 4);
  size_t o_off = o;    o += al((size_t)nAll * 4);
  size_t o_dinv = o;   o += al((size_t)Nb * 4);
  size_t o_bsum = o;   o += al(3 * 256 * 4);
  size_t o_srtbc = o;  o += al((size_t)Ebc * 4);
  size_t o_srtct = o;  o += al((size_t)Ect * 4);
  size_t o_srtadj = o; o += al((size_t)Eadj * 4);
  size_t o_es1 = o;    o += al((size_t)Nb * 16);
  size_t o_ed1 = o;    o += al((size_t)Nc * 16);
  size_t o_es2 = o;    o += al((size_t)Nc * 16);
  size_t o_ed2 = o;    o += al((size_t)Nt * 16);
  size_t o_hs2 = o;    o += al((size_t)Nc * 256);
  size_t o_XW = o;     o += al((size_t)Nb * 256);
  size_t endB = o;
  size_t o_XWg = o;    o += al((size_t)Nb * 256);
  size_t endA = o;
  if (endB > ws_size) return;
  const bool pathA = (endA <= ws_size);

  const uint32_t* det = (const uint32_t*)Ws1;
  __hip_bfloat16* WT = (__hip_bfloat16*)(base + o_WT);
  int* cnt = (int*)(base + o_cnt);
  int* cur = (int*)(base + o_cur);
  int* off = (int*)(base + o_off);
  float* dinv = (float*)(base + o_dinv);
  int* bsum = (int*)(base + o_bsum);
  int* srt_bc = (int*)(base + o_srtbc);
  int* srt_ct = (int*)(base + o_srtct);
  int* srt_adj = (int*)(base + o_srtadj);
  float* es1 = (float*)(base + o_es1);
  float* ed1 = (float*)(base + o_ed1);
  float* es2 = (float*)(base + o_es2);
  float* ed2 = (float*)(base + o_ed2);
  __hip_bfloat16* hs2 = (__hip_bfloat16*)(base + o_hs2);
  __hip_bfloat16* XW = (__hip_bfloat16*)(base + o_XW);
  __hip_bfloat16* XWg = (__hip_bfloat16*)(base + o_XWg);

  const size_t off_b_out = 0;
  const size_t off_c_out = (size_t)Nb * 128;
  const size_t off_t_out = off_c_out + (size_t)Nc * 128;

  // seg order in cnt/cur/off: [cable(Nc) | transformer(Nt) | building(Nb)]
  int* cnt_c = cnt;
  int* cnt_t = cnt + Nc;
  int* cnt_b = cnt + Nc + Nt;
  int* off_c = off;
  int* off_t = off + Nc;
  int* off_b = off + Nc + Nt;

  // L0: zero cnt+cur (contiguous) via async memset (graph-capturable)
  hipMemsetAsync(base + o_cnt, 0, o_off - o_cnt, stream);

  // L1: fused weight transpose + edge histogram
  int Ghist = (Eall + 255) / 256;
  prep_k<<<320 + Ghist, 256, 0, stream>>>(Ws1, Wd1, Ws2, Wd2, Wg, WT, b2c_dst, Ebc,
                                          c2t_dst, Ect, adj_dst, Eadj, cnt, Nc, Nt, Nb,
                                          det);

  // L2-L4: batched scans (+dinv)
  int nb0 = (Nc + 1023) / 1024, nb1 = (Nt + 1023) / 1024, nb2 = (Nb + 1023) / 1024;
  scanp_all<<<nb0 + nb1 + nb2, 256, 0, stream>>>(cnt, off, bsum, Nc, Nt, Nb, nb0, nb1);
  scans_all<<<3, 256, 0, stream>>>(bsum, nb0, nb1, nb2);
  scanadd_dinv<<<(nAll + 255) / 256, 256, 0, stream>>>(off, bsum, cnt, dinv, Nc, Nt, Nb);

  // fill job (shared by both paths)
  FillJ fj;
  fj.s0 = b2c_src; fj.d0 = b2c_dst; fj.s1 = c2t_src; fj.d1 = c2t_dst;
  fj.s2 = adj_src; fj.d2 = adj_dst;
  fj.E0 = Ebc; fj.E1 = Ect; fj.E2 = Eadj;
  fj.off = off; fj.cur = cur;
  fj.r0 = srt_bc; fj.r1 = srt_ct; fj.r2 = srt_adj;
  fj.n0 = Nc; fj.n1 = Nt; fj.n2 = Nb;
  int Gfill = (Eall + 255) / 256;

  int g0 = (Nb + 63) / 64, g1 = (Nc + 63) / 64, g2 = (Nt + 63) / 64;

  // L5: fused GEMM #1 + fill.
  // slots: xb@Ws1->XW(+es1) [dual: also xb@Wg->XWg], xc@Wd1->ed1, xt@Wd2->ed2
  {
    MMB p;
    p.A0 = xb; p.ao0 = 0; p.W0 = WT + 0 * 16384; p.O0 = XW;      p.E0 = es1; p.V0 = a_s1; p.M0 = Nb;
    p.A1 = xc; p.ao1 = 0; p.W1 = WT + 1 * 16384; p.O1 = nullptr; p.E1 = ed1; p.V1 = a_d1; p.M1 = Nc;
    p.A2 = xt; p.ao2 = 0; p.W2 = WT + 3 * 16384; p.O2 = nullptr; p.E2 = ed2; p.V2 = a_d2; p.M2 = Nt;
    p.A3 = xb; p.ao3 = 0; p.W3 = WT + 4 * 16384; p.O3 = pathA ? XWg : nullptr;
    p.E3 = nullptr; p.V3 = nullptr; p.M3 = Nb;
    p.B1 = g0; p.B2 = g0 + g1; p.B3 = BIG;
    p.dual = pathA ? 1 : 0;
    int Gmm = g0 + g1 + g2;
    mm_fill<<<Gmm + Gfill, 256, 0, stream>>>(p, fj, Gmm, det);
  }

  // agg jobs
  AggJob ja1;  // GAT phase 1: building -> cable
  ja1.off = off_c; ja1.cnt = cnt_c; ja1.ssrc = srt_bc; ja1.tab = XW;
  ja1.es = es1; ja1.ed = ed1; ja1.dinv = nullptr;
  ja1.xdst = xc; ja1.bias = b1; ja1.outb = d_out; ja1.ooff = off_c_out;
  ja1.nt_out = 0; ja1.N = Nc; ja1.Ns = Nb; ja1.E = Ebc; ja1.isGcn = 0;
  int Ga1 = (Nc + 3) / 4;

  AggJob jg;  // GCN: building adjacency
  jg.off = off_b; jg.cnt = cnt_b; jg.ssrc = srt_adj;
  jg.tab = pathA ? XWg : XW;
  jg.es = nullptr; jg.ed = nullptr; jg.dinv = dinv;
  jg.xdst = xb; jg.bias = bg; jg.outb = d_out; jg.ooff = off_b_out;
  jg.nt_out = 1; jg.N = Nb; jg.Ns = Nb; jg.E = Eadj; jg.isGcn = 1;
  int Gg = (Nb + 3) / 4;

  AggJob ja2;  // GAT phase 2: cable -> transformer
  ja2.off = off_t; ja2.cnt = cnt_t; ja2.ssrc = srt_ct; ja2.tab = hs2;
  ja2.es = es2; ja2.ed = ed2; ja2.dinv = nullptr;
  ja2.xdst = xt; ja2.bias = b2; ja2.outb = d_out; ja2.ooff = off_t_out;
  ja2.nt_out = 1; ja2.N = Nt; ja2.Ns = Nc; ja2.E = Ect; ja2.isGcn = 0;
  int Ga2 = (Nt + 3) / 4;

  if (pathA) {
    // L6: gcn (long) + gat1 (short) fused — independent after L5
    agg_pair<<<Gg + Ga1, 256, 0, stream>>>(jg, ja1, Gg, det);
    // L7: GEMM #2: h_cable@Ws2 -> hs2 (+es2)
    MMB p;
    p.A0 = d_out; p.ao0 = off_c_out; p.W0 = WT + 2 * 16384; p.O0 = hs2; p.E0 = es2; p.V0 = a_s2; p.M0 = Nc;
    p.A1 = nullptr; p.ao1 = 0; p.W1 = nullptr; p.O1 = nullptr; p.E1 = nullptr; p.V1 = nullptr; p.M1 = 0;
    p.A2 = nullptr; p.ao2 = 0; p.W2 = nullptr; p.O2 = nullptr; p.E2 = nullptr; p.V2 = nullptr; p.M2 = 0;
    p.A3 = nullptr; p.ao3 = 0; p.W3 = nullptr; p.O3 = nullptr; p.E3 = nullptr; p.V3 = nullptr; p.M3 = 0;
    p.B1 = BIG; p.B2 = BIG; p.B3 = BIG; p.dual = 0;
    mm_fill<<<g1, 256, 0, stream>>>(p, fj, g1, det);
    // L8: gat2 alone
    agg_pair<<<Ga2, 256, 0, stream>>>(ja2, ja2, Ga2, det);
  } else {
    // L6: gat1 alone
    agg_pair<<<Ga1, 256, 0, stream>>>(ja1, ja1, Ga1, det);
    // L7: GEMM #2: h_cable@Ws2 -> hs2 (+es2), xb@Wg -> XW (XW free after gat1)
    MMB p;
    p.A0 = d_out; p.ao0 = off_c_out; p.W0 = WT + 2 * 16384; p.O0 = hs2; p.E0 = es2; p.V0 = a_s2; p.M0 = Nc;
    p.A1 = xb; p.ao1 = 0; p.W1 = WT + 4 * 16384; p.O1 = XW; p.E1 = nullptr; p.V1 = nullptr; p.M1 = Nb;
    p.A2 = nullptr; p.ao2 = 0; p.W2 = nullptr; p.O2 = nullptr; p.E2 = nullptr; p.V2 = nullptr; p.M2 = 0;
    p.A3 = nullptr; p.ao3 = 0; p.W3 = nullptr; p.O3 = nullptr; p.E3 = nullptr; p.V3 = nullptr; p.M3 = 0;
    p.B1 = g1; p.B2 = BIG; p.B3 = BIG; p.dual = 0;
    mm_fill<<<g1 + g0, 256, 0, stream>>>(p, fj, g1 + g0, det);
    // L8: gcn (long) + gat2 (short) fused
    agg_pair<<<Gg + Ga2, 256, 0, stream>>>(jg, ja2, Gg, det);
  }
}